// Round 2
// baseline (385.103 us; speedup 1.0000x reference)
//
#include <hip/hip_runtime.h>

// SimpleRasterizer: B=1, V=600, F=1000, H=W=128, K=8.
// d_in[0] = vertices (1,600,3) float32 ; d_in[1] = faces (1,1000,3) int32
// d_out (float32, flat, concat in return order):
//   pix_to_face (1,128,128,8)   : 131072
//   zbuf        (1,128,128,8)   : 131072
//   bary        (1,128,128,8,3) : 393216
//   dists       (1,128,128,8)   : 131072
//
// One thread per pixel; block = 64 threads = one 8x8 pixel tile (tight tile
// bbox -> whole-wave execz skip on the bbox cull for most faces). All face
// data staged in LDS once per block (broadcast reads in the main loop).
// fp32 with contraction OFF + IEEE divides to mirror the numpy float32
// reference op-for-op (sign flips in the inside test would swap indices).

#define HW_    128
#define KF     8
#define NPIX   (HW_ * HW_)
#define EPSf   1e-8f
#define BIGf   1e10f
#define MAXF   1024
#define BBMARG 1e-4f   // cull margin: exact-arithmetic safety vs fp32 rounding

__device__ __forceinline__ float edge_d2_fn(float px, float py,
                                            float ax, float ay,
                                            float bx, float by) {
#pragma clang fp contract(off)
    float ex = bx - ax;
    float ey = by - ay;
    float l2 = fmaxf(ex * ex + ey * ey, EPSf);
    float t  = ((px - ax) * ex + (py - ay) * ey) / l2;
    t = fminf(fmaxf(t, 0.0f), 1.0f);
    float dx = px - (ax + t * ex);
    float dy = py - (ay + t * ey);
    return dx * dx + dy * dy;
}

__global__ __launch_bounds__(64) void raster_kernel(
    const float* __restrict__ verts,
    const int* __restrict__ faces,
    float* __restrict__ out,
    int F)
{
#pragma clang fp contract(off)
    // geo: x0,y0,z0,x1,y1,z1,x2,y2,z2,area   bb: xmin,xmax,ymin,ymax
    __shared__ float geo[10][MAXF];
    __shared__ float bb[4][MAXF];

    // ---- stage all faces into LDS (gather + pixel-independent precompute) ----
    for (int f = threadIdx.x; f < F; f += 64) {
        int i0 = faces[3 * f + 0];
        int i1 = faces[3 * f + 1];
        int i2 = faces[3 * f + 2];
        float x0 = verts[3 * i0 + 0];
        float y0 = verts[3 * i0 + 1];
        float z0 = verts[3 * i0 + 2];
        float x1 = verts[3 * i1 + 0];
        float y1 = verts[3 * i1 + 1];
        float z1 = verts[3 * i1 + 2];
        float x2 = verts[3 * i2 + 0];
        float y2 = verts[3 * i2 + 1];
        float z2 = verts[3 * i2 + 2];
        geo[0][f] = x0; geo[1][f] = y0; geo[2][f] = z0;
        geo[3][f] = x1; geo[4][f] = y1; geo[5][f] = z1;
        geo[6][f] = x2; geo[7][f] = y2; geo[8][f] = z2;
        // area is pixel-independent; identical rounded value to the reference
        float area = (x1 - x0) * (y2 - y0) - (y1 - y0) * (x2 - x0);
        geo[9][f] = area;
        bb[0][f] = fminf(x0, fminf(x1, x2)) - BBMARG;
        bb[1][f] = fmaxf(x0, fmaxf(x1, x2)) + BBMARG;
        bb[2][f] = fminf(y0, fminf(y1, y2)) - BBMARG;
        bb[3][f] = fmaxf(y0, fmaxf(y1, y2)) + BBMARG;
    }
    __syncthreads();

    // ---- pixel for this thread: 8x8 tile per block ----
    int tile = blockIdx.x;                       // 0..255, 16x16 tiles
    int w = (tile & 15) * 8 + (threadIdx.x & 7);
    int h = (tile >> 4) * 8 + (threadIdx.x >> 3);
    float px = 1.0f - (2.0f * ((float)w + 0.5f)) / 128.0f;   // exact dyadic
    float py = 1.0f - (2.0f * ((float)h + 0.5f)) / 128.0f;

    // ---- top-8 (smallest z, stable by face index) in registers ----
    float tz[KF];
    int   ti[KF];
#pragma unroll
    for (int k = 0; k < KF; ++k) { tz[k] = BIGf; ti[k] = -1; }

    for (int f = 0; f < F; ++f) {
        float xmin = bb[0][f], xmax = bb[1][f];
        float ymin = bb[2][f], ymax = bb[3][f];
        if (px < xmin || px > xmax || py < ymin || py > ymax) continue;

        float x0 = geo[0][f], y0 = geo[1][f], z0 = geo[2][f];
        float x1 = geo[3][f], y1 = geo[4][f], z1 = geo[5][f];
        float x2 = geo[6][f], y2 = geo[7][f], z2 = geo[8][f];
        float area = geo[9][f];

        float w0 = (x2 - x1) * (py - y1) - (y2 - y1) * (px - x1);
        float w1 = (x0 - x2) * (py - y2) - (y0 - y2) * (px - x2);
        float w2 = (x1 - x0) * (py - y0) - (y1 - y0) * (px - x0);
        float aabs = fabsf(area);
        float area_safe = (aabs < EPSf) ? EPSf : area;
        float b0 = w0 / area_safe;
        float b1 = w1 / area_safe;
        float b2 = w2 / area_safe;
        if (!(b0 >= 0.0f && b1 >= 0.0f && b2 >= 0.0f && aabs > EPSf)) continue;

        float n0 = b0 * z1 * z2;
        float n1 = z0 * b1 * z2;
        float n2 = z0 * z1 * b2;
        float den = n0 + n1 + n2;
        float dabs = fabsf(den);
        float den_safe = (dabs < EPSf) ? EPSf : den;
        float p0 = n0 / den_safe;
        float p1 = n1 / den_safe;
        float p2 = n2 / den_safe;
        float z = p0 * z0 + p1 * z1 + p2 * z2;

        // stable top-K insert: strict < so equal-z keeps the earlier face index
        if (z < tz[KF - 1]) {
            tz[KF - 1] = z;
            ti[KF - 1] = f;
#pragma unroll
            for (int k = KF - 1; k > 0; --k) {
                bool sw = tz[k] < tz[k - 1];
                float az = sw ? tz[k - 1] : tz[k];
                float bz = sw ? tz[k]     : tz[k - 1];
                int   ai = sw ? ti[k - 1] : ti[k];
                int   bi = sw ? ti[k]     : ti[k - 1];
                tz[k] = az; tz[k - 1] = bz;
                ti[k] = ai; ti[k - 1] = bi;
            }
        }
    }

    // ---- epilogue: recompute bary/dists for the <=8 selected faces ----
    int pix  = h * HW_ + w;
    int base = pix * KF;
    float* o_pix = out;
    float* o_z   = out + NPIX * KF;
    float* o_b   = out + 2 * NPIX * KF;
    float* o_d   = out + 2 * NPIX * KF + NPIX * KF * 3;

#pragma unroll
    for (int k = 0; k < KF; ++k) {
        float zk = tz[k];
        int   f  = ti[k];
        float vp = -1.0f, vz = -1.0f, vb0 = -1.0f, vb1 = -1.0f, vb2 = -1.0f, vd = -1.0f;
        if (zk < 0.5f * BIGf) {
            float x0 = geo[0][f], y0 = geo[1][f], z0 = geo[2][f];
            float x1 = geo[3][f], y1 = geo[4][f], z1 = geo[5][f];
            float x2 = geo[6][f], y2 = geo[7][f], z2 = geo[8][f];
            float area = geo[9][f];
            float w0 = (x2 - x1) * (py - y1) - (y2 - y1) * (px - x1);
            float w1 = (x0 - x2) * (py - y2) - (y0 - y2) * (px - x2);
            float w2 = (x1 - x0) * (py - y0) - (y1 - y0) * (px - x0);
            float aabs = fabsf(area);
            float area_safe = (aabs < EPSf) ? EPSf : area;
            float b0 = w0 / area_safe;
            float b1 = w1 / area_safe;
            float b2 = w2 / area_safe;
            float n0 = b0 * z1 * z2;
            float n1 = z0 * b1 * z2;
            float n2 = z0 * z1 * b2;
            float den = n0 + n1 + n2;
            float dabs = fabsf(den);
            float den_safe = (dabs < EPSf) ? EPSf : den;
            float p0 = n0 / den_safe;
            float p1 = n1 / den_safe;
            float p2 = n2 / den_safe;
            float e0 = edge_d2_fn(px, py, x0, y0, x1, y1);
            float e1 = edge_d2_fn(px, py, x1, y1, x2, y2);
            float e2 = edge_d2_fn(px, py, x2, y2, x0, y0);
            float d2 = fminf(e0, fminf(e1, e2));
            vp = (float)f;
            vz = zk;
            vb0 = p0; vb1 = p1; vb2 = p2;
            vd = -d2;                       // selected faces are inside
        }
        o_pix[base + k] = vp;
        o_z[base + k]   = vz;
        o_b[(base + k) * 3 + 0] = vb0;
        o_b[(base + k) * 3 + 1] = vb1;
        o_b[(base + k) * 3 + 2] = vb2;
        o_d[base + k]   = vd;
    }
}

extern "C" void kernel_launch(void* const* d_in, const int* in_sizes, int n_in,
                              void* d_out, int out_size, void* d_ws, size_t ws_size,
                              hipStream_t stream) {
    const float* verts = (const float*)d_in[0];
    const int* faces = (const int*)d_in[1];
    float* out = (float*)d_out;
    int F = in_sizes[1] / 3;   // 1000
    raster_kernel<<<dim3(256), dim3(64), 0, stream>>>(verts, faces, out, F);
}

// Round 3
// 128.213 us; speedup vs baseline: 3.0036x; 3.0036x over previous
//
#include <hip/hip_runtime.h>

// SimpleRasterizer: B=1, V=600, F=1000, H=W=128, K=8.  (see round-2 notes)
// Round 3: face-parallel waves. Block = 512 thr = 64 pixels x 8 face-chunks,
// grid = 256 tiles -> 8 waves/CU (was 1). Per-thread register top-8 over its
// chunk, then in-block bitonic merge of packed (z_bits,idx) u64 keys
// (z > 0 for accepted faces -> IEEE bits order-monotonic; (z,idx) lexicographic
// == stable lax.top_k). Merge LDS aliases geometry LDS; epilogue re-reads the
// 36 KB verts/faces from global (L2-resident). fp32, contraction OFF, IEEE
// divides -> bit-identical to the numpy reference (round 2 absmax 0.0039).

#define HW_    128
#define KF     8
#define NPIX   (HW_ * HW_)
#define EPSf   1e-8f
#define BIGf   1e10f
#define MAXF   1024
#define CH     8
#define BBMARG 1e-4f

typedef unsigned long long ull;

#define CE(X, Y) { ull _mn = (X) < (Y) ? (X) : (Y); ull _mx = (X) < (Y) ? (Y) : (X); (X) = _mn; (Y) = _mx; }

__device__ __forceinline__ void merge_lists(ull* cand, int ca, int cb, int p) {
    // merge two sorted-ascending 8-lists, keep smallest 8, write into list ca
    ull a[8], b[8], c[8];
#pragma unroll
    for (int i = 0; i < 8; ++i) a[i] = cand[(ca * 64 + p) * 8 + i];
#pragma unroll
    for (int i = 0; i < 8; ++i) b[i] = cand[(cb * 64 + p) * 8 + i];
#pragma unroll
    for (int i = 0; i < 8; ++i) { ull x = a[i], y = b[7 - i]; c[i] = x < y ? x : y; }
    // c is bitonic; sort ascending with bitonic-merge network (4,2,1)
    CE(c[0], c[4]); CE(c[1], c[5]); CE(c[2], c[6]); CE(c[3], c[7]);
    CE(c[0], c[2]); CE(c[1], c[3]); CE(c[4], c[6]); CE(c[5], c[7]);
    CE(c[0], c[1]); CE(c[2], c[3]); CE(c[4], c[5]); CE(c[6], c[7]);
#pragma unroll
    for (int i = 0; i < 8; ++i) cand[(ca * 64 + p) * 8 + i] = c[i];
}

__device__ __forceinline__ float edge_d2_fn(float px, float py,
                                            float ax, float ay,
                                            float bx, float by) {
#pragma clang fp contract(off)
    float ex = bx - ax;
    float ey = by - ay;
    float l2 = fmaxf(ex * ex + ey * ey, EPSf);
    float t  = ((px - ax) * ex + (py - ay) * ey) / l2;
    t = fminf(fmaxf(t, 0.0f), 1.0f);
    float dx = px - (ax + t * ex);
    float dy = py - (ay + t * ey);
    return dx * dx + dy * dy;
}

__global__ __launch_bounds__(512) void raster_kernel(
    const float* __restrict__ verts,
    const int* __restrict__ faces,
    float* __restrict__ out,
    int F)
{
#pragma clang fp contract(off)
    // LDS map (56 KB): ga 16K | gb 16K | gz 8K | bb 16K ; cand (32K) aliases ga+gb
    __shared__ __align__(16) char smem[57344];
    float4* ga = (float4*)smem;                  // x0,y0,x1,y1
    float4* gb = (float4*)(smem + 16384);        // x2,y2,z0,z1
    float2* gz = (float2*)(smem + 32768);        // z2, area
    float4* bb = (float4*)(smem + 40960);        // xmin,xmax,ymin,ymax
    ull*    cand = (ull*)smem;                   // [8][64][8] keys, post-loop

    int tid  = threadIdx.x;
    int tile = blockIdx.x;                       // 16x16 tiles of 8x8 pixels

    // ---- stage all faces (4 vec-stores per face) ----
    for (int f = tid; f < F; f += 512) {
        int i0 = faces[3 * f + 0];
        int i1 = faces[3 * f + 1];
        int i2 = faces[3 * f + 2];
        float x0 = verts[3 * i0 + 0], y0 = verts[3 * i0 + 1], z0 = verts[3 * i0 + 2];
        float x1 = verts[3 * i1 + 0], y1 = verts[3 * i1 + 1], z1 = verts[3 * i1 + 2];
        float x2 = verts[3 * i2 + 0], y2 = verts[3 * i2 + 1], z2 = verts[3 * i2 + 2];
        ga[f] = make_float4(x0, y0, x1, y1);
        gb[f] = make_float4(x2, y2, z0, z1);
        float area = (x1 - x0) * (y2 - y0) - (y1 - y0) * (x2 - x0);
        gz[f] = make_float2(z2, area);
        bb[f] = make_float4(fminf(x0, fminf(x1, x2)) - BBMARG,
                            fmaxf(x0, fmaxf(x1, x2)) + BBMARG,
                            fminf(y0, fminf(y1, y2)) - BBMARG,
                            fmaxf(y0, fmaxf(y1, y2)) + BBMARG);
    }
    __syncthreads();

    // ---- main loop: thread = (pixel in 8x8 tile) x (face chunk) ----
    int p = tid & 63;
    int c = tid >> 6;
    int w = (tile & 15) * 8 + (p & 7);
    int h = (tile >> 4) * 8 + (p >> 3);
    float px = 1.0f - (2.0f * ((float)w + 0.5f)) / 128.0f;
    float py = 1.0f - (2.0f * ((float)h + 0.5f)) / 128.0f;

    float tz[KF];
    int   ti[KF];
#pragma unroll
    for (int k = 0; k < KF; ++k) { tz[k] = BIGf; ti[k] = -1; }

    int f0 = (F * c) / CH;
    int f1 = (F * (c + 1)) / CH;
    for (int f = f0; f < f1; ++f) {
        float4 B4 = bb[f];
        if (px < B4.x || px > B4.y || py < B4.z || py > B4.w) continue;

        float4 A  = ga[f];
        float4 Bv = gb[f];
        float2 Zz = gz[f];
        float x0 = A.x,  y0 = A.y,  x1 = A.z,  y1 = A.w;
        float x2 = Bv.x, y2 = Bv.y, z0 = Bv.z, z1 = Bv.w;
        float z2 = Zz.x, area = Zz.y;

        float w0 = (x2 - x1) * (py - y1) - (y2 - y1) * (px - x1);
        float w1 = (x0 - x2) * (py - y2) - (y0 - y2) * (px - x2);
        float w2 = (x1 - x0) * (py - y0) - (y1 - y0) * (px - x0);
        float aabs = fabsf(area);
        float area_safe = (aabs < EPSf) ? EPSf : area;
        float b0 = w0 / area_safe;
        float b1 = w1 / area_safe;
        float b2 = w2 / area_safe;
        if (!(b0 >= 0.0f && b1 >= 0.0f && b2 >= 0.0f && aabs > EPSf)) continue;

        float n0 = b0 * z1 * z2;
        float n1 = z0 * b1 * z2;
        float n2 = z0 * z1 * b2;
        float den = n0 + n1 + n2;
        float dabs = fabsf(den);
        float den_safe = (dabs < EPSf) ? EPSf : den;
        float p0 = n0 / den_safe;
        float p1 = n1 / den_safe;
        float p2 = n2 / den_safe;
        float z = p0 * z0 + p1 * z1 + p2 * z2;

        if (z < tz[KF - 1]) {        // stable: strict <, ascending f within chunk
            tz[KF - 1] = z;
            ti[KF - 1] = f;
#pragma unroll
            for (int k = KF - 1; k > 0; --k) {
                bool sw = tz[k] < tz[k - 1];
                float az = sw ? tz[k - 1] : tz[k];
                float bz = sw ? tz[k]     : tz[k - 1];
                int   ai = sw ? ti[k - 1] : ti[k];
                int   bi = sw ? ti[k]     : ti[k - 1];
                tz[k] = az; tz[k - 1] = bz;
                ti[k] = ai; ti[k - 1] = bi;
            }
        }
    }

    // ---- publish per-chunk sorted keys (cand aliases ga/gb: sync first) ----
    __syncthreads();
#pragma unroll
    for (int k = 0; k < KF; ++k)
        cand[(c * 64 + p) * 8 + k] =
            ((ull)__float_as_uint(tz[k]) << 32) | (ull)(unsigned)ti[k];
    __syncthreads();

    // ---- merge tree: 8 -> 4 -> 2 -> 1 (result in list 0) ----
    if (tid < 256) { int pp = tid & 63, r = tid >> 6; merge_lists(cand, 2 * r, 2 * r + 1, pp); }
    __syncthreads();
    if (tid < 128) { int pp = tid & 63, r = tid >> 6; merge_lists(cand, 4 * r, 4 * r + 2, pp); }
    __syncthreads();
    if (tid < 64)  { merge_lists(cand, 0, 4, tid); }
    __syncthreads();

    // ---- epilogue: 512 threads = 64 pixels x 8 slots, geometry from global ----
    int pp = tid >> 3;
    int k  = tid & 7;
    ull key = cand[pp * 8 + k];
    unsigned idxu = (unsigned)(key & 0xFFFFFFFFULL);
    float zk = __uint_as_float((unsigned)(key >> 32));

    int w2i = (tile & 15) * 8 + (pp & 7);
    int h2i = (tile >> 4) * 8 + (pp >> 3);
    float qx = 1.0f - (2.0f * ((float)w2i + 0.5f)) / 128.0f;
    float qy = 1.0f - (2.0f * ((float)h2i + 0.5f)) / 128.0f;
    int base = (h2i * HW_ + w2i) * KF;

    float vp = -1.0f, vz = -1.0f, vb0 = -1.0f, vb1 = -1.0f, vb2 = -1.0f, vd = -1.0f;
    if (idxu != 0xFFFFFFFFu) {
        int f = (int)idxu;
        int i0 = faces[3 * f + 0];
        int i1 = faces[3 * f + 1];
        int i2 = faces[3 * f + 2];
        float x0 = verts[3 * i0 + 0], y0 = verts[3 * i0 + 1], z0 = verts[3 * i0 + 2];
        float x1 = verts[3 * i1 + 0], y1 = verts[3 * i1 + 1], z1 = verts[3 * i1 + 2];
        float x2 = verts[3 * i2 + 0], y2 = verts[3 * i2 + 1], z2 = verts[3 * i2 + 2];
        float area = (x1 - x0) * (y2 - y0) - (y1 - y0) * (x2 - x0);
        float w0 = (x2 - x1) * (qy - y1) - (y2 - y1) * (qx - x1);
        float w1 = (x0 - x2) * (qy - y2) - (y0 - y2) * (qx - x2);
        float w2 = (x1 - x0) * (qy - y0) - (y1 - y0) * (qx - x0);
        float aabs = fabsf(area);
        float area_safe = (aabs < EPSf) ? EPSf : area;
        float b0 = w0 / area_safe;
        float b1 = w1 / area_safe;
        float b2 = w2 / area_safe;
        float n0 = b0 * z1 * z2;
        float n1 = z0 * b1 * z2;
        float n2 = z0 * z1 * b2;
        float den = n0 + n1 + n2;
        float dabs = fabsf(den);
        float den_safe = (dabs < EPSf) ? EPSf : den;
        float p0 = n0 / den_safe;
        float p1 = n1 / den_safe;
        float p2 = n2 / den_safe;
        float e0 = edge_d2_fn(qx, qy, x0, y0, x1, y1);
        float e1 = edge_d2_fn(qx, qy, x1, y1, x2, y2);
        float e2 = edge_d2_fn(qx, qy, x2, y2, x0, y0);
        float d2 = fminf(e0, fminf(e1, e2));
        vp = (float)f;
        vz = zk;
        vb0 = p0; vb1 = p1; vb2 = p2;
        vd = -d2;                       // selected faces are inside
    }

    float* o_pix = out;
    float* o_z   = out + NPIX * KF;
    float* o_b   = out + 2 * NPIX * KF;
    float* o_d   = out + 2 * NPIX * KF + NPIX * KF * 3;
    o_pix[base + k] = vp;
    o_z[base + k]   = vz;
    o_b[(base + k) * 3 + 0] = vb0;
    o_b[(base + k) * 3 + 1] = vb1;
    o_b[(base + k) * 3 + 2] = vb2;
    o_d[base + k]   = vd;
}

extern "C" void kernel_launch(void* const* d_in, const int* in_sizes, int n_in,
                              void* d_out, int out_size, void* d_ws, size_t ws_size,
                              hipStream_t stream) {
    const float* verts = (const float*)d_in[0];
    const int* faces = (const int*)d_in[1];
    float* out = (float*)d_out;
    int F = in_sizes[1] / 3;   // 1000
    raster_kernel<<<dim3(256), dim3(512), 0, stream>>>(verts, faces, out, F);
}

// Round 4
// 115.932 us; speedup vs baseline: 3.3218x; 1.1059x over previous
//
#include <hip/hip_runtime.h>

// SimpleRasterizer: B=1, V=600, F=1000, H=W=128, K=8.
// Round 4: occupancy + divide-latency + LDS-conflict fixes.
//  - grid 512 x block 512: tile = 8x4 pixels (32) x 16 face-chunks
//    -> 2 blocks/CU x 8 waves = 16 waves/CU (was 8).
//  - inside test via exact sign tests (w*sign(area) >= 0  <=>  w/area >= 0,
//    incl. +-0; divides only issued for inside lanes -> same bits as ref).
//  - cand keys in SoA [slot][list][pixel]: lane stride 8B -> no bank conflicts.
// fp32, contraction OFF, IEEE divides -> matches numpy reference op-for-op.

#define HW_    128
#define KF     8
#define NPIX   (HW_ * HW_)
#define EPSf   1e-8f
#define BIGf   1e10f
#define CH     16
#define NPB    32      // pixels per block (8x4)
#define BBMARG 1e-4f

typedef unsigned long long ull;

#define CE(X, Y) { ull _mn = (X) < (Y) ? (X) : (Y); ull _mx = (X) < (Y) ? (Y) : (X); (X) = _mn; (Y) = _mx; }

// cand layout: cand[k*512 + list*32 + p]  (k=slot 0..7, list 0..15, p=pixel 0..31)
__device__ __forceinline__ void merge_lists(ull* cand, int la, int lb, int p) {
    ull a[8], b[8], c[8];
#pragma unroll
    for (int i = 0; i < 8; ++i) a[i] = cand[i * 512 + la * 32 + p];
#pragma unroll
    for (int i = 0; i < 8; ++i) b[i] = cand[i * 512 + lb * 32 + p];
#pragma unroll
    for (int i = 0; i < 8; ++i) { ull x = a[i], y = b[7 - i]; c[i] = x < y ? x : y; }
    CE(c[0], c[4]); CE(c[1], c[5]); CE(c[2], c[6]); CE(c[3], c[7]);
    CE(c[0], c[2]); CE(c[1], c[3]); CE(c[4], c[6]); CE(c[5], c[7]);
    CE(c[0], c[1]); CE(c[2], c[3]); CE(c[4], c[5]); CE(c[6], c[7]);
#pragma unroll
    for (int i = 0; i < 8; ++i) cand[i * 512 + la * 32 + p] = c[i];
}

__device__ __forceinline__ float edge_d2_fn(float px, float py,
                                            float ax, float ay,
                                            float bx, float by) {
#pragma clang fp contract(off)
    float ex = bx - ax;
    float ey = by - ay;
    float l2 = fmaxf(ex * ex + ey * ey, EPSf);
    float t  = ((px - ax) * ex + (py - ay) * ey) / l2;
    t = fminf(fmaxf(t, 0.0f), 1.0f);
    float dx = px - (ax + t * ex);
    float dy = py - (ay + t * ey);
    return dx * dx + dy * dy;
}

__global__ __launch_bounds__(512) void raster_kernel(
    const float* __restrict__ verts,
    const int* __restrict__ faces,
    float* __restrict__ out,
    int F)
{
#pragma clang fp contract(off)
    // LDS map (56 KB): ga 16K | gb 16K | gz 8K | bb 16K ; cand (32K) aliases ga+gb
    __shared__ __align__(16) char smem[57344];
    float4* ga = (float4*)smem;                  // x0,y0,x1,y1
    float4* gb = (float4*)(smem + 16384);        // x2,y2,z0,z1
    float2* gz = (float2*)(smem + 32768);        // z2, area
    float4* bb = (float4*)(smem + 40960);        // xmin,xmax,ymin,ymax
    ull*    cand = (ull*)smem;                   // [8][16][32] keys, post-loop

    int tid  = threadIdx.x;
    int tile = blockIdx.x;                       // 16 x-tiles (8px) x 32 y-tiles (4px)

    // ---- stage all faces (4 vec-stores per face; 2 iters/thread) ----
    for (int f = tid; f < F; f += 512) {
        int i0 = faces[3 * f + 0];
        int i1 = faces[3 * f + 1];
        int i2 = faces[3 * f + 2];
        float x0 = verts[3 * i0 + 0], y0 = verts[3 * i0 + 1], z0 = verts[3 * i0 + 2];
        float x1 = verts[3 * i1 + 0], y1 = verts[3 * i1 + 1], z1 = verts[3 * i1 + 2];
        float x2 = verts[3 * i2 + 0], y2 = verts[3 * i2 + 1], z2 = verts[3 * i2 + 2];
        ga[f] = make_float4(x0, y0, x1, y1);
        gb[f] = make_float4(x2, y2, z0, z1);
        float area = (x1 - x0) * (y2 - y0) - (y1 - y0) * (x2 - x0);
        gz[f] = make_float2(z2, area);
        bb[f] = make_float4(fminf(x0, fminf(x1, x2)) - BBMARG,
                            fmaxf(x0, fmaxf(x1, x2)) + BBMARG,
                            fminf(y0, fminf(y1, y2)) - BBMARG,
                            fmaxf(y0, fmaxf(y1, y2)) + BBMARG);
    }
    __syncthreads();

    // ---- main loop: thread = (pixel in 8x4 tile) x (face chunk of ~62) ----
    int p = tid & 31;
    int c = tid >> 5;
    int w = (tile & 15) * 8 + (p & 7);
    int h = (tile >> 4) * 4 + (p >> 3);
    float px = 1.0f - (2.0f * ((float)w + 0.5f)) / 128.0f;
    float py = 1.0f - (2.0f * ((float)h + 0.5f)) / 128.0f;

    float tz[KF];
    int   ti[KF];
#pragma unroll
    for (int k = 0; k < KF; ++k) { tz[k] = BIGf; ti[k] = -1; }

    int f0 = (F * c) / CH;
    int f1 = (F * (c + 1)) / CH;
    for (int f = f0; f < f1; ++f) {
        float4 B4 = bb[f];
        if (px < B4.x || px > B4.y || py < B4.z || py > B4.w) continue;

        float4 A  = ga[f];
        float4 Bv = gb[f];
        float2 Zz = gz[f];
        float x0 = A.x,  y0 = A.y,  x1 = A.z,  y1 = A.w;
        float x2 = Bv.x, y2 = Bv.y, z0 = Bv.z, z1 = Bv.w;
        float z2 = Zz.x, area = Zz.y;

        float w0 = (x2 - x1) * (py - y1) - (y2 - y1) * (px - x1);
        float w1 = (x0 - x2) * (py - y2) - (y0 - y2) * (px - x2);
        float w2 = (x1 - x0) * (py - y0) - (y1 - y0) * (px - x0);
        float aabs = fabsf(area);
        // exact sign-equivalent of (w0/area>=0 && w1/area>=0 && w2/area>=0):
        float s = (area > 0.0f) ? 1.0f : -1.0f;
        if (!(w0 * s >= 0.0f && w1 * s >= 0.0f && w2 * s >= 0.0f && aabs > EPSf))
            continue;

        float area_safe = area;                  // aabs > EPS here
        float b0 = w0 / area_safe;
        float b1 = w1 / area_safe;
        float b2 = w2 / area_safe;
        float n0 = b0 * z1 * z2;
        float n1 = z0 * b1 * z2;
        float n2 = z0 * z1 * b2;
        float den = n0 + n1 + n2;
        float dabs = fabsf(den);
        float den_safe = (dabs < EPSf) ? EPSf : den;
        float p0 = n0 / den_safe;
        float p1 = n1 / den_safe;
        float p2 = n2 / den_safe;
        float z = p0 * z0 + p1 * z1 + p2 * z2;

        if (z < tz[KF - 1]) {        // stable: strict <, ascending f within chunk
            tz[KF - 1] = z;
            ti[KF - 1] = f;
#pragma unroll
            for (int k = KF - 1; k > 0; --k) {
                bool sw = tz[k] < tz[k - 1];
                float az = sw ? tz[k - 1] : tz[k];
                float bz = sw ? tz[k]     : tz[k - 1];
                int   ai = sw ? ti[k - 1] : ti[k];
                int   bi = sw ? ti[k]     : ti[k - 1];
                tz[k] = az; tz[k - 1] = bz;
                ti[k] = ai; ti[k - 1] = bi;
            }
        }
    }

    // ---- publish per-chunk sorted keys (cand aliases ga/gb: sync first) ----
    __syncthreads();
#pragma unroll
    for (int k = 0; k < KF; ++k)
        cand[k * 512 + c * 32 + p] =
            ((ull)__float_as_uint(tz[k]) << 32) | (ull)(unsigned)ti[k];
    __syncthreads();

    // ---- merge tree: 16 -> 8 -> 4 -> 2 -> 1 (result in list 0) ----
    if (tid < 256) { int pp = tid & 31, r = tid >> 5; merge_lists(cand,  2 * r,  2 * r + 1, pp); }
    __syncthreads();
    if (tid < 128) { int pp = tid & 31, r = tid >> 5; merge_lists(cand,  4 * r,  4 * r + 2, pp); }
    __syncthreads();
    if (tid < 64)  { int pp = tid & 31, r = tid >> 5; merge_lists(cand,  8 * r,  8 * r + 4, pp); }
    __syncthreads();
    if (tid < 32)  { merge_lists(cand, 0, 8, tid); }
    __syncthreads();

    // ---- epilogue: 256 threads = 32 pixels x 8 slots, geometry from global ----
    if (tid < NPB * KF) {
        int pp = tid >> 3;
        int k  = tid & 7;
        ull key = cand[k * 512 + pp];
        unsigned idxu = (unsigned)(key & 0xFFFFFFFFULL);
        float zk = __uint_as_float((unsigned)(key >> 32));

        int w2i = (tile & 15) * 8 + (pp & 7);
        int h2i = (tile >> 4) * 4 + (pp >> 3);
        float qx = 1.0f - (2.0f * ((float)w2i + 0.5f)) / 128.0f;
        float qy = 1.0f - (2.0f * ((float)h2i + 0.5f)) / 128.0f;
        int base = (h2i * HW_ + w2i) * KF;

        float vp = -1.0f, vz = -1.0f, vb0 = -1.0f, vb1 = -1.0f, vb2 = -1.0f, vd = -1.0f;
        if (idxu != 0xFFFFFFFFu) {
            int f = (int)idxu;
            int i0 = faces[3 * f + 0];
            int i1 = faces[3 * f + 1];
            int i2 = faces[3 * f + 2];
            float x0 = verts[3 * i0 + 0], y0 = verts[3 * i0 + 1], z0 = verts[3 * i0 + 2];
            float x1 = verts[3 * i1 + 0], y1 = verts[3 * i1 + 1], z1 = verts[3 * i1 + 2];
            float x2 = verts[3 * i2 + 0], y2 = verts[3 * i2 + 1], z2 = verts[3 * i2 + 2];
            float area = (x1 - x0) * (y2 - y0) - (y1 - y0) * (x2 - x0);
            float w0 = (x2 - x1) * (qy - y1) - (y2 - y1) * (qx - x1);
            float w1 = (x0 - x2) * (qy - y2) - (y0 - y2) * (qx - x2);
            float w2 = (x1 - x0) * (qy - y0) - (y1 - y0) * (qx - x0);
            float aabs = fabsf(area);
            float area_safe = (aabs < EPSf) ? EPSf : area;
            float b0 = w0 / area_safe;
            float b1 = w1 / area_safe;
            float b2 = w2 / area_safe;
            float n0 = b0 * z1 * z2;
            float n1 = z0 * b1 * z2;
            float n2 = z0 * z1 * b2;
            float den = n0 + n1 + n2;
            float dabs = fabsf(den);
            float den_safe = (dabs < EPSf) ? EPSf : den;
            float p0 = n0 / den_safe;
            float p1 = n1 / den_safe;
            float p2 = n2 / den_safe;
            float e0 = edge_d2_fn(qx, qy, x0, y0, x1, y1);
            float e1 = edge_d2_fn(qx, qy, x1, y1, x2, y2);
            float e2 = edge_d2_fn(qx, qy, x2, y2, x0, y0);
            float d2 = fminf(e0, fminf(e1, e2));
            vp = (float)f;
            vz = zk;
            vb0 = p0; vb1 = p1; vb2 = p2;
            vd = -d2;                       // selected faces are inside
        }

        float* o_pix = out;
        float* o_z   = out + NPIX * KF;
        float* o_b   = out + 2 * NPIX * KF;
        float* o_d   = out + 2 * NPIX * KF + NPIX * KF * 3;
        o_pix[base + k] = vp;
        o_z[base + k]   = vz;
        o_b[(base + k) * 3 + 0] = vb0;
        o_b[(base + k) * 3 + 1] = vb1;
        o_b[(base + k) * 3 + 2] = vb2;
        o_d[base + k]   = vd;
    }
}

extern "C" void kernel_launch(void* const* d_in, const int* in_sizes, int n_in,
                              void* d_out, int out_size, void* d_ws, size_t ws_size,
                              hipStream_t stream) {
    const float* verts = (const float*)d_in[0];
    const int* faces = (const int*)d_in[1];
    float* out = (float*)d_out;
    int F = in_sizes[1] / 3;   // 1000
    raster_kernel<<<dim3(512), dim3(512), 0, stream>>>(verts, faces, out, F);
}

// Round 5
// 104.498 us; speedup vs baseline: 3.6853x; 1.1094x over previous
//
#include <hip/hip_runtime.h>

// SimpleRasterizer: B=1, V=600, F=1000, H=W=128, K=8.
// Round 5: tile-level face compaction.
//  - grid 1024 (32x32 tiles of 4x4 px) x block 512 = 16 pixels x 32 chunks.
//  - staging culls each face against the tile rect (same BBMARG margin as the
//    per-pixel test it replaces -> strictly more permissive, never mis-culls),
//    then order-preserving ballot+prefix compaction into LDS (~280 survivors).
//  - main loop: ~9 dense iterations/thread over compacted geometry, no
//    per-pixel bbox reads; sign-test gates the divide chain (round-4 trick).
//  - LDS 48 KB -> 3 blocks/CU; __launch_bounds__(512,6) holds 24 waves/CU.
// fp32, contraction OFF, IEEE divides -> matches numpy reference op-for-op.

#define HW_    128
#define KF     8
#define NPIX   (HW_ * HW_)
#define EPSf   1e-8f
#define BIGf   1e10f
#define NPB    16      // pixels per block (4x4)
#define CH     32      // face chunks per block
#define BBMARG 1e-4f

typedef unsigned long long ull;

#define CE(X, Y) { ull _mn = (X) < (Y) ? (X) : (Y); ull _mx = (X) < (Y) ? (Y) : (X); (X) = _mn; (Y) = _mx; }

// cand layout: cand[k*512 + list*16 + p]  (k=slot 0..7, list 0..31, p=pixel 0..15)
__device__ __forceinline__ void merge_lists(ull* cand, int la, int lb, int p) {
    ull a[8], b[8], c[8];
#pragma unroll
    for (int i = 0; i < 8; ++i) a[i] = cand[i * 512 + la * 16 + p];
#pragma unroll
    for (int i = 0; i < 8; ++i) b[i] = cand[i * 512 + lb * 16 + p];
#pragma unroll
    for (int i = 0; i < 8; ++i) { ull x = a[i], y = b[7 - i]; c[i] = x < y ? x : y; }
    CE(c[0], c[4]); CE(c[1], c[5]); CE(c[2], c[6]); CE(c[3], c[7]);
    CE(c[0], c[2]); CE(c[1], c[3]); CE(c[4], c[6]); CE(c[5], c[7]);
    CE(c[0], c[1]); CE(c[2], c[3]); CE(c[4], c[5]); CE(c[6], c[7]);
#pragma unroll
    for (int i = 0; i < 8; ++i) cand[i * 512 + la * 16 + p] = c[i];
}

__device__ __forceinline__ float edge_d2_fn(float px, float py,
                                            float ax, float ay,
                                            float bx, float by) {
#pragma clang fp contract(off)
    float ex = bx - ax;
    float ey = by - ay;
    float l2 = fmaxf(ex * ex + ey * ey, EPSf);
    float t  = ((px - ax) * ex + (py - ay) * ey) / l2;
    t = fminf(fmaxf(t, 0.0f), 1.0f);
    float dx = px - (ax + t * ex);
    float dy = py - (ay + t * ey);
    return dx * dx + dy * dy;
}

__global__ __launch_bounds__(512, 6) void raster_kernel(
    const float* __restrict__ verts,
    const int* __restrict__ faces,
    float* __restrict__ out,
    int F)
{
#pragma clang fp contract(off)
    // LDS map (48 KB + 32 B): ga 16K | gb 16K | gzf 16K | wtot 32B
    // cand (32K) aliases ga+gb after the main loop.
    __shared__ __align__(16) char smem[49216];
    float4*   ga   = (float4*)smem;                  // x0,y0,x1,y1 (compacted)
    float4*   gb   = (float4*)(smem + 16384);        // x2,y2,z0,z1
    float4*   gzf  = (float4*)(smem + 32768);        // z2,area,face_idx,0
    unsigned* wtot = (unsigned*)(smem + 49152);      // per-wave keep counts
    ull*      cand = (ull*)smem;                     // [8][32][16] keys

    int tid  = threadIdx.x;
    int tile = blockIdx.x;                           // 32 x-tiles x 32 y-tiles
    int txi = tile & 31, tyi = tile >> 5;

    // tile NDC rect (pixel-center extremes; px/py decrease with w/h)
    float pxhi = 1.0f - (2.0f * ((float)(txi * 4)     + 0.5f)) / 128.0f;
    float pxlo = 1.0f - (2.0f * ((float)(txi * 4 + 3) + 0.5f)) / 128.0f;
    float pyhi = 1.0f - (2.0f * ((float)(tyi * 4)     + 0.5f)) / 128.0f;
    float pylo = 1.0f - (2.0f * ((float)(tyi * 4 + 3) + 0.5f)) / 128.0f;

    int lane = tid & 63;
    int wv   = tid >> 6;
    int S = 0;                                       // compacted survivor count

    // ---- stage + tile-cull + order-preserving compaction ----
    for (int fbase = 0; fbase < F; fbase += 512) {
        int f = fbase + tid;
        bool keep = false;
        float x0=0,y0=0,z0=0,x1=0,y1=0,z1=0,x2=0,y2=0,z2=0,area=0;
        if (f < F) {
            int i0 = faces[3 * f + 0];
            int i1 = faces[3 * f + 1];
            int i2 = faces[3 * f + 2];
            x0 = verts[3 * i0 + 0]; y0 = verts[3 * i0 + 1]; z0 = verts[3 * i0 + 2];
            x1 = verts[3 * i1 + 0]; y1 = verts[3 * i1 + 1]; z1 = verts[3 * i1 + 2];
            x2 = verts[3 * i2 + 0]; y2 = verts[3 * i2 + 1]; z2 = verts[3 * i2 + 2];
            area = (x1 - x0) * (y2 - y0) - (y1 - y0) * (x2 - x0);
            float xmn = fminf(x0, fminf(x1, x2)) - BBMARG;
            float xmx = fmaxf(x0, fmaxf(x1, x2)) + BBMARG;
            float ymn = fminf(y0, fminf(y1, y2)) - BBMARG;
            float ymx = fmaxf(y0, fmaxf(y1, y2)) + BBMARG;
            keep = (xmn <= pxhi) && (xmx >= pxlo) && (ymn <= pyhi) && (ymx >= pylo);
        }
        ull bal = __ballot(keep);
        int below = __popcll(bal & ((1ull << lane) - 1ull));
        if (lane == 0) wtot[wv] = (unsigned)__popcll(bal);
        __syncthreads();
        int pre = 0, tot = 0;
#pragma unroll
        for (int w8 = 0; w8 < 8; ++w8) {
            int t = (int)wtot[w8];
            if (w8 < wv) pre += t;
            tot += t;
        }
        if (keep) {
            int pos = S + pre + below;
            ga[pos]  = make_float4(x0, y0, x1, y1);
            gb[pos]  = make_float4(x2, y2, z0, z1);
            gzf[pos] = make_float4(z2, area, (float)f, 0.0f);
        }
        S += tot;
        __syncthreads();   // wtot reuse next round + geometry visibility
    }

    // ---- main loop: thread = (pixel in 4x4 tile) x (chunk of ~S/32 faces) ----
    int p = tid & 15;
    int c = tid >> 4;
    int w = txi * 4 + (p & 3);
    int h = tyi * 4 + (p >> 2);
    float px = 1.0f - (2.0f * ((float)w + 0.5f)) / 128.0f;
    float py = 1.0f - (2.0f * ((float)h + 0.5f)) / 128.0f;

    float tz[KF];
    int   ti_[KF];
#pragma unroll
    for (int k = 0; k < KF; ++k) { tz[k] = BIGf; ti_[k] = -1; }

    int j0 = (S * c) / CH;
    int j1 = (S * (c + 1)) / CH;
    for (int j = j0; j < j1; ++j) {
        float4 A  = ga[j];
        float4 Bv = gb[j];
        float4 Zf = gzf[j];
        float x0 = A.x,  y0 = A.y,  x1 = A.z,  y1 = A.w;
        float x2 = Bv.x, y2 = Bv.y, z0 = Bv.z, z1 = Bv.w;
        float z2 = Zf.x, area = Zf.y;

        float w0 = (x2 - x1) * (py - y1) - (y2 - y1) * (px - x1);
        float w1 = (x0 - x2) * (py - y2) - (y0 - y2) * (px - x2);
        float w2 = (x1 - x0) * (py - y0) - (y1 - y0) * (px - x0);
        float aabs = fabsf(area);
        // exact sign-equivalent of (w0/area>=0 && w1/area>=0 && w2/area>=0)
        float s = (area > 0.0f) ? 1.0f : -1.0f;
        if (!(w0 * s >= 0.0f && w1 * s >= 0.0f && w2 * s >= 0.0f && aabs > EPSf))
            continue;

        float b0 = w0 / area;
        float b1 = w1 / area;
        float b2 = w2 / area;
        float n0 = b0 * z1 * z2;
        float n1 = z0 * b1 * z2;
        float n2 = z0 * z1 * b2;
        float den = n0 + n1 + n2;
        float dabs = fabsf(den);
        float den_safe = (dabs < EPSf) ? EPSf : den;
        float p0 = n0 / den_safe;
        float p1 = n1 / den_safe;
        float p2 = n2 / den_safe;
        float z = p0 * z0 + p1 * z1 + p2 * z2;

        if (z < tz[KF - 1]) {        // stable: strict <, ascending f within chunk
            int fidx = (int)Zf.z;
            tz[KF - 1] = z;
            ti_[KF - 1] = fidx;
#pragma unroll
            for (int k = KF - 1; k > 0; --k) {
                bool sw = tz[k] < tz[k - 1];
                float az = sw ? tz[k - 1] : tz[k];
                float bz = sw ? tz[k]     : tz[k - 1];
                int   ai = sw ? ti_[k - 1] : ti_[k];
                int   bi = sw ? ti_[k]     : ti_[k - 1];
                tz[k] = az; tz[k - 1] = bz;
                ti_[k] = ai; ti_[k - 1] = bi;
            }
        }
    }

    // ---- publish per-chunk sorted keys (cand aliases ga/gb: sync first) ----
    __syncthreads();
#pragma unroll
    for (int k = 0; k < KF; ++k)
        cand[k * 512 + c * 16 + p] =
            ((ull)__float_as_uint(tz[k]) << 32) | (ull)(unsigned)ti_[k];
    __syncthreads();

    // ---- merge tree: 32 -> 16 -> 8 -> 4 -> 2 -> 1 (result in list 0) ----
    if (tid < 256) { int pp = tid & 15, r = tid >> 4; merge_lists(cand,  2 * r,  2 * r + 1, pp); }
    __syncthreads();
    if (tid < 128) { int pp = tid & 15, r = tid >> 4; merge_lists(cand,  4 * r,  4 * r + 2, pp); }
    __syncthreads();
    if (tid < 64)  { int pp = tid & 15, r = tid >> 4; merge_lists(cand,  8 * r,  8 * r + 4, pp); }
    __syncthreads();
    if (tid < 32)  { int pp = tid & 15, r = tid >> 4; merge_lists(cand, 16 * r, 16 * r + 8, pp); }
    __syncthreads();
    if (tid < 16)  { merge_lists(cand, 0, 16, tid); }
    __syncthreads();

    // ---- epilogue: 128 threads = 16 pixels x 8 slots, geometry from global ----
    if (tid < NPB * KF) {
        int pp = tid >> 3;
        int k  = tid & 7;
        ull key = cand[k * 512 + pp];
        unsigned idxu = (unsigned)(key & 0xFFFFFFFFULL);
        float zk = __uint_as_float((unsigned)(key >> 32));

        int w2i = txi * 4 + (pp & 3);
        int h2i = tyi * 4 + (pp >> 2);
        float qx = 1.0f - (2.0f * ((float)w2i + 0.5f)) / 128.0f;
        float qy = 1.0f - (2.0f * ((float)h2i + 0.5f)) / 128.0f;
        int base = (h2i * HW_ + w2i) * KF;

        float vp = -1.0f, vz = -1.0f, vb0 = -1.0f, vb1 = -1.0f, vb2 = -1.0f, vd = -1.0f;
        if (idxu != 0xFFFFFFFFu) {
            int f = (int)idxu;
            int i0 = faces[3 * f + 0];
            int i1 = faces[3 * f + 1];
            int i2 = faces[3 * f + 2];
            float x0 = verts[3 * i0 + 0], y0 = verts[3 * i0 + 1], z0 = verts[3 * i0 + 2];
            float x1 = verts[3 * i1 + 0], y1 = verts[3 * i1 + 1], z1 = verts[3 * i1 + 2];
            float x2 = verts[3 * i2 + 0], y2 = verts[3 * i2 + 1], z2 = verts[3 * i2 + 2];
            float area = (x1 - x0) * (y2 - y0) - (y1 - y0) * (x2 - x0);
            float w0 = (x2 - x1) * (qy - y1) - (y2 - y1) * (qx - x1);
            float w1 = (x0 - x2) * (qy - y2) - (y0 - y2) * (qx - x2);
            float w2 = (x1 - x0) * (qy - y0) - (y1 - y0) * (qx - x0);
            float aabs = fabsf(area);
            float area_safe = (aabs < EPSf) ? EPSf : area;
            float b0 = w0 / area_safe;
            float b1 = w1 / area_safe;
            float b2 = w2 / area_safe;
            float n0 = b0 * z1 * z2;
            float n1 = z0 * b1 * z2;
            float n2 = z0 * z1 * b2;
            float den = n0 + n1 + n2;
            float dabs = fabsf(den);
            float den_safe = (dabs < EPSf) ? EPSf : den;
            float p0 = n0 / den_safe;
            float p1 = n1 / den_safe;
            float p2 = n2 / den_safe;
            float e0 = edge_d2_fn(qx, qy, x0, y0, x1, y1);
            float e1 = edge_d2_fn(qx, qy, x1, y1, x2, y2);
            float e2 = edge_d2_fn(qx, qy, x2, y2, x0, y0);
            float d2 = fminf(e0, fminf(e1, e2));
            vp = (float)f;
            vz = zk;
            vb0 = p0; vb1 = p1; vb2 = p2;
            vd = -d2;                       // selected faces are inside
        }

        float* o_pix = out;
        float* o_z   = out + NPIX * KF;
        float* o_b   = out + 2 * NPIX * KF;
        float* o_d   = out + 2 * NPIX * KF + NPIX * KF * 3;
        o_pix[base + k] = vp;
        o_z[base + k]   = vz;
        o_b[(base + k) * 3 + 0] = vb0;
        o_b[(base + k) * 3 + 1] = vb1;
        o_b[(base + k) * 3 + 2] = vb2;
        o_d[base + k]   = vd;
    }
}

extern "C" void kernel_launch(void* const* d_in, const int* in_sizes, int n_in,
                              void* d_out, int out_size, void* d_ws, size_t ws_size,
                              hipStream_t stream) {
    const float* verts = (const float*)d_in[0];
    const int* faces = (const int*)d_in[1];
    float* out = (float*)d_out;
    int F = in_sizes[1] / 3;   // 1000
    raster_kernel<<<dim3(1024), dim3(512), 0, stream>>>(verts, faces, out, F);
}

// Round 6
// 88.951 us; speedup vs baseline: 4.3294x; 1.1748x over previous
//
#include <hip/hip_runtime.h>

// SimpleRasterizer: B=1, V=600, F=1000, H=W=128, K=8.
// Round 6: preprocess kernel + affine edge tile-cull + full occupancy.
//  - kernel A (4 blocks): per-face bbox(+1e-4), s-premultiplied affine edge
//    coeffs (w_e*s = A_e + B_e*py + C_e*px), packed geometry -> d_ws (7xfloat4).
//  - kernel B staging: 4 coalesced b128 loads + rect-max edge test
//    (cull iff max_rect(s*w_e) < -1e-3 for some edge; margin >> fp error ->
//    never culls a reference-inside face). Survivors ~110-130 (was ~300).
//  - survivor cap 512 -> geometry LDS 24 KB, cand 32 KB aliases it ->
//    LDS 32.1 KB -> 4 blocks/CU x 8 waves = 32 waves/CU, grid fully resident.
// Selection math unchanged (exact fp32, contraction OFF, IEEE divides).

#define HW_    128
#define KF     8
#define NPIX   (HW_ * HW_)
#define EPSf   1e-8f
#define BIGf   1e10f
#define NPB    16      // pixels per block (4x4)
#define CH     32      // face chunks per block
#define SCAP   512     // survivor capacity (mean ~125 worst tile, +35 sigma)
#define BBMARG 1e-4f
#define EDGEM  1e-3f

typedef unsigned long long ull;

#define CE(X, Y) { ull _mn = (X) < (Y) ? (X) : (Y); ull _mx = (X) < (Y) ? (Y) : (X); (X) = _mn; (Y) = _mx; }

// cand layout: cand[k*512 + list*16 + p]  (k=slot 0..7, list 0..31, p=pixel 0..15)
__device__ __forceinline__ void merge_lists(ull* cand, int la, int lb, int p) {
    ull a[8], b[8], c[8];
#pragma unroll
    for (int i = 0; i < 8; ++i) a[i] = cand[i * 512 + la * 16 + p];
#pragma unroll
    for (int i = 0; i < 8; ++i) b[i] = cand[i * 512 + lb * 16 + p];
#pragma unroll
    for (int i = 0; i < 8; ++i) { ull x = a[i], y = b[7 - i]; c[i] = x < y ? x : y; }
    CE(c[0], c[4]); CE(c[1], c[5]); CE(c[2], c[6]); CE(c[3], c[7]);
    CE(c[0], c[2]); CE(c[1], c[3]); CE(c[4], c[6]); CE(c[5], c[7]);
    CE(c[0], c[1]); CE(c[2], c[3]); CE(c[4], c[5]); CE(c[6], c[7]);
#pragma unroll
    for (int i = 0; i < 8; ++i) cand[i * 512 + la * 16 + p] = c[i];
}

__device__ __forceinline__ float edge_d2_fn(float px, float py,
                                            float ax, float ay,
                                            float bx, float by) {
#pragma clang fp contract(off)
    float ex = bx - ax;
    float ey = by - ay;
    float l2 = fmaxf(ex * ex + ey * ey, EPSf);
    float t  = ((px - ax) * ex + (py - ay) * ey) / l2;
    t = fminf(fmaxf(t, 0.0f), 1.0f);
    float dx = px - (ax + t * ex);
    float dy = py - (ay + t * ey);
    return dx * dx + dy * dy;
}

// ---------------- kernel A: per-face preprocessing -> ws ----------------
// ws4[f*7 + 0] = bbox (xmn-m, xmx+m, ymn-m, ymx+m)
// ws4[f*7 + 1..3] = s*(A_e, B_e, C_e) per edge, .w unused
// ws4[f*7 + 4] = (x0,y0,x1,y1)  5 = (x2,y2,z0,z1)  6 = (z2, area, f, 0)
__global__ __launch_bounds__(256) void preprocess_kernel(
    const float* __restrict__ verts,
    const int* __restrict__ faces,
    float4* __restrict__ ws4,
    int F)
{
#pragma clang fp contract(off)
    int f = blockIdx.x * 256 + threadIdx.x;
    if (f >= F) return;
    int i0 = faces[3 * f + 0];
    int i1 = faces[3 * f + 1];
    int i2 = faces[3 * f + 2];
    float x0 = verts[3 * i0 + 0], y0 = verts[3 * i0 + 1], z0 = verts[3 * i0 + 2];
    float x1 = verts[3 * i1 + 0], y1 = verts[3 * i1 + 1], z1 = verts[3 * i1 + 2];
    float x2 = verts[3 * i2 + 0], y2 = verts[3 * i2 + 1], z2 = verts[3 * i2 + 2];
    float area = (x1 - x0) * (y2 - y0) - (y1 - y0) * (x2 - x0);  // exact ref expr
    float s = (area > 0.0f) ? 1.0f : -1.0f;
    // w0 = (x2-x1)(py-y1) - (y2-y1)(px-x1) = A0 + B0*py + C0*px
    float B0 = (x2 - x1), C0 = -(y2 - y1), A0 = (y2 - y1) * x1 - (x2 - x1) * y1;
    float B1 = (x0 - x2), C1 = -(y0 - y2), A1 = (y0 - y2) * x2 - (x0 - x2) * y2;
    float B2 = (x1 - x0), C2 = -(y1 - y0), A2 = (y1 - y0) * x0 - (x1 - x0) * y0;
    float4* p = ws4 + f * 7;
    p[0] = make_float4(fminf(x0, fminf(x1, x2)) - BBMARG,
                       fmaxf(x0, fmaxf(x1, x2)) + BBMARG,
                       fminf(y0, fminf(y1, y2)) - BBMARG,
                       fmaxf(y0, fmaxf(y1, y2)) + BBMARG);
    p[1] = make_float4(s * A0, s * B0, s * C0, 0.0f);
    p[2] = make_float4(s * A1, s * B1, s * C1, 0.0f);
    p[3] = make_float4(s * A2, s * B2, s * C2, 0.0f);
    p[4] = make_float4(x0, y0, x1, y1);
    p[5] = make_float4(x2, y2, z0, z1);
    p[6] = make_float4(z2, area, (float)f, 0.0f);
}

// ---------------- kernel B: rasterize ----------------
__global__ __launch_bounds__(512, 8) void raster_kernel(
    const float4* __restrict__ ws4,
    float* __restrict__ out,
    int F)
{
#pragma clang fp contract(off)
    // LDS: geometry (24 KB, live through main loop) aliased by cand (32 KB,
    // live after) -> 32.25 KB total -> 4 blocks/CU.
    __shared__ __align__(16) char smem[32832];
    float4*   ga   = (float4*)smem;                    // x0,y0,x1,y1 (compacted)
    float4*   gb   = (float4*)(smem + 8192);           // x2,y2,z0,z1
    float4*   gzf  = (float4*)(smem + 16384);          // z2,area,face_idx,0
    unsigned* wtot = (unsigned*)(smem + 32768);        // per-wave keep counts
    ull*      cand = (ull*)smem;                       // [8][32][16] keys

    int tid  = threadIdx.x;
    int tile = blockIdx.x;                             // 32 x-tiles x 32 y-tiles
    int txi = tile & 31, tyi = tile >> 5;

    // tile NDC rect (pixel-center extremes; px/py decrease with w/h)
    float pxhi = 1.0f - (2.0f * ((float)(txi * 4)     + 0.5f)) / 128.0f;
    float pxlo = 1.0f - (2.0f * ((float)(txi * 4 + 3) + 0.5f)) / 128.0f;
    float pyhi = 1.0f - (2.0f * ((float)(tyi * 4)     + 0.5f)) / 128.0f;
    float pylo = 1.0f - (2.0f * ((float)(tyi * 4 + 3) + 0.5f)) / 128.0f;

    int lane = tid & 63;
    int wv   = tid >> 6;
    int S = 0;                                         // compacted survivor count

    // ---- stage: bbox + affine edge rect-max cull + order-preserving compaction
    for (int fbase = 0; fbase < F; fbase += 512) {
        int f = fbase + tid;
        bool keep = false;
        const float4* p = ws4 + f * 7;
        if (f < F) {
            float4 b4 = p[0];
            float4 e0 = p[1];
            float4 e1 = p[2];
            float4 e2 = p[3];
            bool bo = (b4.x <= pxhi) && (b4.y >= pxlo) && (b4.z <= pyhi) && (b4.w >= pylo);
            float w0m = e0.x + fmaxf(e0.y * pylo, e0.y * pyhi) + fmaxf(e0.z * pxlo, e0.z * pxhi);
            float w1m = e1.x + fmaxf(e1.y * pylo, e1.y * pyhi) + fmaxf(e1.z * pxlo, e1.z * pxhi);
            float w2m = e2.x + fmaxf(e2.y * pylo, e2.y * pyhi) + fmaxf(e2.z * pxlo, e2.z * pxhi);
            keep = bo && (w0m >= -EDGEM) && (w1m >= -EDGEM) && (w2m >= -EDGEM);
        }
        ull bal = __ballot(keep);
        int below = __popcll(bal & ((1ull << lane) - 1ull));
        if (lane == 0) wtot[wv] = (unsigned)__popcll(bal);
        __syncthreads();
        int pre = 0, tot = 0;
#pragma unroll
        for (int w8 = 0; w8 < 8; ++w8) {
            int t = (int)wtot[w8];
            if (w8 < wv) pre += t;
            tot += t;
        }
        if (keep) {
            int pos = S + pre + below;
            if (pos < SCAP) {                          // +35 sigma headroom
                ga[pos]  = p[4];
                gb[pos]  = p[5];
                gzf[pos] = p[6];
            }
        }
        S += tot;
        if (S > SCAP) S = SCAP;
        __syncthreads();   // wtot reuse next round + geometry visibility
    }

    // ---- main loop: thread = (pixel in 4x4 tile) x (chunk of ~S/32 faces) ----
    int p_ = tid & 15;
    int c = tid >> 4;
    int w = txi * 4 + (p_ & 3);
    int h = tyi * 4 + (p_ >> 2);
    float px = 1.0f - (2.0f * ((float)w + 0.5f)) / 128.0f;
    float py = 1.0f - (2.0f * ((float)h + 0.5f)) / 128.0f;

    float tz[KF];
    int   ti_[KF];
#pragma unroll
    for (int k = 0; k < KF; ++k) { tz[k] = BIGf; ti_[k] = -1; }

    int j0 = (S * c) / CH;
    int j1 = (S * (c + 1)) / CH;
    for (int j = j0; j < j1; ++j) {
        float4 A  = ga[j];
        float4 Bv = gb[j];
        float4 Zf = gzf[j];
        float x0 = A.x,  y0 = A.y,  x1 = A.z,  y1 = A.w;
        float x2 = Bv.x, y2 = Bv.y, z0 = Bv.z, z1 = Bv.w;
        float z2 = Zf.x, area = Zf.y;

        float w0 = (x2 - x1) * (py - y1) - (y2 - y1) * (px - x1);
        float w1 = (x0 - x2) * (py - y2) - (y0 - y2) * (px - x2);
        float w2 = (x1 - x0) * (py - y0) - (y1 - y0) * (px - x0);
        float aabs = fabsf(area);
        // exact sign-equivalent of (w0/area>=0 && w1/area>=0 && w2/area>=0)
        float s = (area > 0.0f) ? 1.0f : -1.0f;
        if (!(w0 * s >= 0.0f && w1 * s >= 0.0f && w2 * s >= 0.0f && aabs > EPSf))
            continue;

        float b0 = w0 / area;
        float b1 = w1 / area;
        float b2 = w2 / area;
        float n0 = b0 * z1 * z2;
        float n1 = z0 * b1 * z2;
        float n2 = z0 * z1 * b2;
        float den = n0 + n1 + n2;
        float dabs = fabsf(den);
        float den_safe = (dabs < EPSf) ? EPSf : den;
        float p0 = n0 / den_safe;
        float p1 = n1 / den_safe;
        float p2 = n2 / den_safe;
        float z = p0 * z0 + p1 * z1 + p2 * z2;

        if (z < tz[KF - 1]) {        // stable: strict <, ascending f within chunk
            int fidx = (int)Zf.z;
            tz[KF - 1] = z;
            ti_[KF - 1] = fidx;
#pragma unroll
            for (int k = KF - 1; k > 0; --k) {
                bool sw = tz[k] < tz[k - 1];
                float az = sw ? tz[k - 1] : tz[k];
                float bz = sw ? tz[k]     : tz[k - 1];
                int   ai = sw ? ti_[k - 1] : ti_[k];
                int   bi = sw ? ti_[k]     : ti_[k - 1];
                tz[k] = az; tz[k - 1] = bz;
                ti_[k] = ai; ti_[k - 1] = bi;
            }
        }
    }

    // ---- publish per-chunk sorted keys (cand aliases geometry: sync first) ----
    __syncthreads();
#pragma unroll
    for (int k = 0; k < KF; ++k)
        cand[k * 512 + c * 16 + p_] =
            ((ull)__float_as_uint(tz[k]) << 32) | (ull)(unsigned)ti_[k];
    __syncthreads();

    // ---- merge tree: 32 -> 16 -> 8 -> 4 -> 2 -> 1 (result in list 0) ----
    if (tid < 256) { int pp = tid & 15, r = tid >> 4; merge_lists(cand,  2 * r,  2 * r + 1, pp); }
    __syncthreads();
    if (tid < 128) { int pp = tid & 15, r = tid >> 4; merge_lists(cand,  4 * r,  4 * r + 2, pp); }
    __syncthreads();
    if (tid < 64)  { int pp = tid & 15, r = tid >> 4; merge_lists(cand,  8 * r,  8 * r + 4, pp); }
    __syncthreads();
    if (tid < 32)  { int pp = tid & 15, r = tid >> 4; merge_lists(cand, 16 * r, 16 * r + 8, pp); }
    __syncthreads();
    if (tid < 16)  { merge_lists(cand, 0, 16, tid); }
    __syncthreads();

    // ---- epilogue: 128 threads = 16 pixels x 8 slots, geometry from ws ----
    if (tid < NPB * KF) {
        int pp = tid >> 3;
        int k  = tid & 7;
        ull key = cand[k * 512 + pp];
        unsigned idxu = (unsigned)(key & 0xFFFFFFFFULL);
        float zk = __uint_as_float((unsigned)(key >> 32));

        int w2i = txi * 4 + (pp & 3);
        int h2i = tyi * 4 + (pp >> 2);
        float qx = 1.0f - (2.0f * ((float)w2i + 0.5f)) / 128.0f;
        float qy = 1.0f - (2.0f * ((float)h2i + 0.5f)) / 128.0f;
        int base = (h2i * HW_ + w2i) * KF;

        float vp = -1.0f, vz = -1.0f, vb0 = -1.0f, vb1 = -1.0f, vb2 = -1.0f, vd = -1.0f;
        if (idxu != 0xFFFFFFFFu) {
            int f = (int)idxu;
            const float4* pw = ws4 + f * 7;
            float4 A4 = pw[4];
            float4 B4 = pw[5];
            float4 Z4 = pw[6];
            float x0 = A4.x, y0 = A4.y, x1 = A4.z, y1 = A4.w;
            float x2 = B4.x, y2 = B4.y, z0 = B4.z, z1 = B4.w;
            float z2 = Z4.x, area = Z4.y;
            float w0 = (x2 - x1) * (qy - y1) - (y2 - y1) * (qx - x1);
            float w1 = (x0 - x2) * (qy - y2) - (y0 - y2) * (qx - x2);
            float w2 = (x1 - x0) * (qy - y0) - (y1 - y0) * (qx - x0);
            float aabs = fabsf(area);
            float area_safe = (aabs < EPSf) ? EPSf : area;
            float b0 = w0 / area_safe;
            float b1 = w1 / area_safe;
            float b2 = w2 / area_safe;
            float n0 = b0 * z1 * z2;
            float n1 = z0 * b1 * z2;
            float n2 = z0 * z1 * b2;
            float den = n0 + n1 + n2;
            float dabs = fabsf(den);
            float den_safe = (dabs < EPSf) ? EPSf : den;
            float p0 = n0 / den_safe;
            float p1 = n1 / den_safe;
            float p2 = n2 / den_safe;
            float e0 = edge_d2_fn(qx, qy, x0, y0, x1, y1);
            float e1 = edge_d2_fn(qx, qy, x1, y1, x2, y2);
            float e2 = edge_d2_fn(qx, qy, x2, y2, x0, y0);
            float d2 = fminf(e0, fminf(e1, e2));
            vp = (float)f;
            vz = zk;
            vb0 = p0; vb1 = p1; vb2 = p2;
            vd = -d2;                       // selected faces are inside
        }

        float* o_pix = out;
        float* o_z   = out + NPIX * KF;
        float* o_b   = out + 2 * NPIX * KF;
        float* o_d   = out + 2 * NPIX * KF + NPIX * KF * 3;
        o_pix[base + k] = vp;
        o_z[base + k]   = vz;
        o_b[(base + k) * 3 + 0] = vb0;
        o_b[(base + k) * 3 + 1] = vb1;
        o_b[(base + k) * 3 + 2] = vb2;
        o_d[base + k]   = vd;
    }
}

extern "C" void kernel_launch(void* const* d_in, const int* in_sizes, int n_in,
                              void* d_out, int out_size, void* d_ws, size_t ws_size,
                              hipStream_t stream) {
    const float* verts = (const float*)d_in[0];
    const int* faces = (const int*)d_in[1];
    float* out = (float*)d_out;
    float4* ws4 = (float4*)d_ws;
    int F = in_sizes[1] / 3;   // 1000
    preprocess_kernel<<<dim3((F + 255) / 256), dim3(256), 0, stream>>>(verts, faces, ws4, F);
    raster_kernel<<<dim3(1024), dim3(512), 0, stream>>>(ws4, out, F);
}

// Round 7
// 86.842 us; speedup vs baseline: 4.4345x; 1.0243x over previous
//
#include <hip/hip_runtime.h>

// SimpleRasterizer: B=1, V=600, F=1000, H=W=128, K=8.
// Round 7: barrier-free top-K merge via wave shuffles.
//  - kernel A unchanged: per-face bbox + s-premultiplied affine edge coeffs +
//    packed geometry -> d_ws (7 x float4 per face).
//  - kernel B: 512 thr = 8 waves; wave owns 2 pixels x 32 chunks (64 lanes).
//    Per-lane top-8 over its chunk as u64 (z_bits<<32|idx) keys (positive z ->
//    IEEE bit order == value order; lexicographic == stable lax.top_k).
//    Cross-chunk merge = 5-round __shfl_xor hypercube all-reduce, keep-low-8:
//    no LDS, no barriers. Only 4 __syncthreads remain (staging/compaction).
//  - LDS 24.6 KB, __launch_bounds__(512,8) -> 4 blocks/CU, grid 1024 resident.
// Geometry math identical to validated rounds (fp32, contraction OFF, IEEE div).

#define HW_    128
#define KF     8
#define NPIX   (HW_ * HW_)
#define EPSf   1e-8f
#define BIGf   1e10f
#define SCAP   512     // survivor capacity per tile
#define BBMARG 1e-4f
#define EDGEM  1e-3f

typedef unsigned long long ull;

#define CE(X, Y) { ull _mn = (X) < (Y) ? (X) : (Y); ull _mx = (X) < (Y) ? (Y) : (X); (X) = _mn; (Y) = _mx; }

__device__ __forceinline__ float edge_d2_fn(float px, float py,
                                            float ax, float ay,
                                            float bx, float by) {
#pragma clang fp contract(off)
    float ex = bx - ax;
    float ey = by - ay;
    float l2 = fmaxf(ex * ex + ey * ey, EPSf);
    float t  = ((px - ax) * ex + (py - ay) * ey) / l2;
    t = fminf(fmaxf(t, 0.0f), 1.0f);
    float dx = px - (ax + t * ex);
    float dy = py - (ay + t * ey);
    return dx * dx + dy * dy;
}

// ---------------- kernel A: per-face preprocessing -> ws ----------------
// ws4[f*7 + 0] = bbox (xmn-m, xmx+m, ymn-m, ymx+m)
// ws4[f*7 + 1..3] = s*(A_e, B_e, C_e) per edge, .w unused
// ws4[f*7 + 4] = (x0,y0,x1,y1)  5 = (x2,y2,z0,z1)  6 = (z2, area, f, 0)
__global__ __launch_bounds__(256) void preprocess_kernel(
    const float* __restrict__ verts,
    const int* __restrict__ faces,
    float4* __restrict__ ws4,
    int F)
{
#pragma clang fp contract(off)
    int f = blockIdx.x * 256 + threadIdx.x;
    if (f >= F) return;
    int i0 = faces[3 * f + 0];
    int i1 = faces[3 * f + 1];
    int i2 = faces[3 * f + 2];
    float x0 = verts[3 * i0 + 0], y0 = verts[3 * i0 + 1], z0 = verts[3 * i0 + 2];
    float x1 = verts[3 * i1 + 0], y1 = verts[3 * i1 + 1], z1 = verts[3 * i1 + 2];
    float x2 = verts[3 * i2 + 0], y2 = verts[3 * i2 + 1], z2 = verts[3 * i2 + 2];
    float area = (x1 - x0) * (y2 - y0) - (y1 - y0) * (x2 - x0);  // exact ref expr
    float s = (area > 0.0f) ? 1.0f : -1.0f;
    // w0 = (x2-x1)(py-y1) - (y2-y1)(px-x1) = A0 + B0*py + C0*px
    float B0 = (x2 - x1), C0 = -(y2 - y1), A0 = (y2 - y1) * x1 - (x2 - x1) * y1;
    float B1 = (x0 - x2), C1 = -(y0 - y2), A1 = (y0 - y2) * x2 - (x0 - x2) * y2;
    float B2 = (x1 - x0), C2 = -(y1 - y0), A2 = (y1 - y0) * x0 - (x1 - x0) * y0;
    float4* p = ws4 + f * 7;
    p[0] = make_float4(fminf(x0, fminf(x1, x2)) - BBMARG,
                       fmaxf(x0, fmaxf(x1, x2)) + BBMARG,
                       fminf(y0, fminf(y1, y2)) - BBMARG,
                       fmaxf(y0, fmaxf(y1, y2)) + BBMARG);
    p[1] = make_float4(s * A0, s * B0, s * C0, 0.0f);
    p[2] = make_float4(s * A1, s * B1, s * C1, 0.0f);
    p[3] = make_float4(s * A2, s * B2, s * C2, 0.0f);
    p[4] = make_float4(x0, y0, x1, y1);
    p[5] = make_float4(x2, y2, z0, z1);
    p[6] = make_float4(z2, area, (float)f, 0.0f);
}

// ---------------- kernel B: rasterize ----------------
__global__ __launch_bounds__(512, 8) void raster_kernel(
    const float4* __restrict__ ws4,
    float* __restrict__ out,
    int F)
{
#pragma clang fp contract(off)
    // LDS: compacted geometry only (24 KB) + wave totals
    __shared__ __align__(16) char smem[24608];
    float4*   ga   = (float4*)smem;                    // x0,y0,x1,y1
    float4*   gb   = (float4*)(smem + 8192);           // x2,y2,z0,z1
    float4*   gzf  = (float4*)(smem + 16384);          // z2,area,face_idx,0
    unsigned* wtot = (unsigned*)(smem + 24576);        // per-wave keep counts

    int tid  = threadIdx.x;
    int tile = blockIdx.x;                             // 32 x-tiles x 32 y-tiles
    int txi = tile & 31, tyi = tile >> 5;

    // tile NDC rect (pixel-center extremes; px/py decrease with w/h)
    float pxhi = 1.0f - (2.0f * ((float)(txi * 4)     + 0.5f)) / 128.0f;
    float pxlo = 1.0f - (2.0f * ((float)(txi * 4 + 3) + 0.5f)) / 128.0f;
    float pyhi = 1.0f - (2.0f * ((float)(tyi * 4)     + 0.5f)) / 128.0f;
    float pylo = 1.0f - (2.0f * ((float)(tyi * 4 + 3) + 0.5f)) / 128.0f;

    int lane = tid & 63;
    int wv   = tid >> 6;
    int S = 0;                                         // compacted survivor count

    // ---- stage: bbox + affine edge rect-max cull + order-preserving compaction
    for (int fbase = 0; fbase < F; fbase += 512) {
        int f = fbase + tid;
        bool keep = false;
        const float4* p = ws4 + f * 7;
        if (f < F) {
            float4 b4 = p[0];
            float4 e0 = p[1];
            float4 e1 = p[2];
            float4 e2 = p[3];
            bool bo = (b4.x <= pxhi) && (b4.y >= pxlo) && (b4.z <= pyhi) && (b4.w >= pylo);
            float w0m = e0.x + fmaxf(e0.y * pylo, e0.y * pyhi) + fmaxf(e0.z * pxlo, e0.z * pxhi);
            float w1m = e1.x + fmaxf(e1.y * pylo, e1.y * pyhi) + fmaxf(e1.z * pxlo, e1.z * pxhi);
            float w2m = e2.x + fmaxf(e2.y * pylo, e2.y * pyhi) + fmaxf(e2.z * pxlo, e2.z * pxhi);
            keep = bo && (w0m >= -EDGEM) && (w1m >= -EDGEM) && (w2m >= -EDGEM);
        }
        ull bal = __ballot(keep);
        int below = __popcll(bal & ((1ull << lane) - 1ull));
        if (lane == 0) wtot[wv] = (unsigned)__popcll(bal);
        __syncthreads();
        int pre = 0, tot = 0;
#pragma unroll
        for (int w8 = 0; w8 < 8; ++w8) {
            int t = (int)wtot[w8];
            if (w8 < wv) pre += t;
            tot += t;
        }
        if (keep) {
            int pos = S + pre + below;
            if (pos < SCAP) {
                ga[pos]  = p[4];
                gb[pos]  = p[5];
                gzf[pos] = p[6];
            }
        }
        S += tot;
        if (S > SCAP) S = SCAP;
        __syncthreads();   // wtot reuse next round; final one = geometry visibility
    }

    // ---- main loop: wave = 2 pixels x 32 chunks; lane -> (pixel, chunk) ----
    int p_ = (wv << 1) | (lane >> 5);                  // pixel 0..15 in 4x4 tile
    int c  = lane & 31;                                // chunk 0..31
    int w = txi * 4 + (p_ & 3);
    int h = tyi * 4 + (p_ >> 2);
    float px = 1.0f - (2.0f * ((float)w + 0.5f)) / 128.0f;
    float py = 1.0f - (2.0f * ((float)h + 0.5f)) / 128.0f;

    const ull SENT = ((ull)0x501502F9u << 32) | 0xFFFFFFFFull;  // (bits(1e10), -1)
    ull tk[KF];
#pragma unroll
    for (int k = 0; k < KF; ++k) tk[k] = SENT;

    int j0 = (S * c) >> 5;
    int j1 = (S * (c + 1)) >> 5;
    for (int j = j0; j < j1; ++j) {
        float4 A  = ga[j];
        float4 Bv = gb[j];
        float4 Zf = gzf[j];
        float x0 = A.x,  y0 = A.y,  x1 = A.z,  y1 = A.w;
        float x2 = Bv.x, y2 = Bv.y, z0 = Bv.z, z1 = Bv.w;
        float z2 = Zf.x, area = Zf.y;

        float w0 = (x2 - x1) * (py - y1) - (y2 - y1) * (px - x1);
        float w1 = (x0 - x2) * (py - y2) - (y0 - y2) * (px - x2);
        float w2 = (x1 - x0) * (py - y0) - (y1 - y0) * (px - x0);
        float aabs = fabsf(area);
        // exact sign-equivalent of (w0/area>=0 && w1/area>=0 && w2/area>=0)
        float s = (area > 0.0f) ? 1.0f : -1.0f;
        if (!(w0 * s >= 0.0f && w1 * s >= 0.0f && w2 * s >= 0.0f && aabs > EPSf))
            continue;

        float b0 = w0 / area;
        float b1 = w1 / area;
        float b2 = w2 / area;
        float n0 = b0 * z1 * z2;
        float n1 = z0 * b1 * z2;
        float n2 = z0 * z1 * b2;
        float den = n0 + n1 + n2;
        float dabs = fabsf(den);
        float den_safe = (dabs < EPSf) ? EPSf : den;
        float p0 = n0 / den_safe;
        float p1 = n1 / den_safe;
        float p2 = n2 / den_safe;
        float z = p0 * z0 + p1 * z1 + p2 * z2;

        // u64 (z,idx) key: order-independent stable top-8 insert
        ull key = ((ull)__float_as_uint(z) << 32) | (ull)(unsigned)(int)Zf.z;
        if (key < tk[KF - 1]) {
            tk[KF - 1] = key;
#pragma unroll
            for (int k = KF - 1; k > 0; --k) CE(tk[k - 1], tk[k]);
        }
    }

    // ---- cross-chunk merge: 5-round hypercube shuffle all-reduce, no barriers
#pragma unroll
    for (int d = 1; d < 32; d <<= 1) {
        ull cc[KF];
#pragma unroll
        for (int i = 0; i < KF; ++i) {
            ull bv = (ull)__shfl_xor((long long)tk[KF - 1 - i], d, 64);
            cc[i] = tk[i] < bv ? tk[i] : bv;
        }
        // cc is bitonic; ascending bitonic-merge network (4,2,1)
        CE(cc[0], cc[4]); CE(cc[1], cc[5]); CE(cc[2], cc[6]); CE(cc[3], cc[7]);
        CE(cc[0], cc[2]); CE(cc[1], cc[3]); CE(cc[4], cc[6]); CE(cc[5], cc[7]);
        CE(cc[0], cc[1]); CE(cc[2], cc[3]); CE(cc[4], cc[5]); CE(cc[6], cc[7]);
#pragma unroll
        for (int i = 0; i < KF; ++i) tk[i] = cc[i];
    }
    // all 32 lanes of each pixel-group now hold the identical sorted top-8

    // ---- epilogue: lanes (lane&31)<8 handle slot (lane&7) of their pixel ----
    int sub = lane & 31;
    ull key = tk[0];
#pragma unroll
    for (int k = 1; k < KF; ++k) key = (sub == k) ? tk[k] : key;

    if (sub < KF) {
        int k = sub;
        unsigned idxu = (unsigned)(key & 0xFFFFFFFFULL);
        float zk = __uint_as_float((unsigned)(key >> 32));
        int base = (h * HW_ + w) * KF;

        float vp = -1.0f, vz = -1.0f, vb0 = -1.0f, vb1 = -1.0f, vb2 = -1.0f, vd = -1.0f;
        if (idxu != 0xFFFFFFFFu && zk < 0.5f * BIGf) {
            int f = (int)idxu;
            const float4* pw = ws4 + f * 7;
            float4 A4 = pw[4];
            float4 B4 = pw[5];
            float4 Z4 = pw[6];
            float x0 = A4.x, y0 = A4.y, x1 = A4.z, y1 = A4.w;
            float x2 = B4.x, y2 = B4.y, z0 = B4.z, z1 = B4.w;
            float z2 = Z4.x, area = Z4.y;
            float w0 = (x2 - x1) * (py - y1) - (y2 - y1) * (px - x1);
            float w1 = (x0 - x2) * (py - y2) - (y0 - y2) * (px - x2);
            float w2 = (x1 - x0) * (py - y0) - (y1 - y0) * (px - x0);
            float aabs = fabsf(area);
            float area_safe = (aabs < EPSf) ? EPSf : area;
            float b0 = w0 / area_safe;
            float b1 = w1 / area_safe;
            float b2 = w2 / area_safe;
            float n0 = b0 * z1 * z2;
            float n1 = z0 * b1 * z2;
            float n2 = z0 * z1 * b2;
            float den = n0 + n1 + n2;
            float dabs = fabsf(den);
            float den_safe = (dabs < EPSf) ? EPSf : den;
            float p0 = n0 / den_safe;
            float p1 = n1 / den_safe;
            float p2 = n2 / den_safe;
            float e0 = edge_d2_fn(px, py, x0, y0, x1, y1);
            float e1 = edge_d2_fn(px, py, x1, y1, x2, y2);
            float e2 = edge_d2_fn(px, py, x2, y2, x0, y0);
            float d2 = fminf(e0, fminf(e1, e2));
            vp = (float)f;
            vz = zk;
            vb0 = p0; vb1 = p1; vb2 = p2;
            vd = -d2;                       // selected faces are inside
        }

        float* o_pix = out;
        float* o_z   = out + NPIX * KF;
        float* o_b   = out + 2 * NPIX * KF;
        float* o_d   = out + 2 * NPIX * KF + NPIX * KF * 3;
        o_pix[base + k] = vp;
        o_z[base + k]   = vz;
        o_b[(base + k) * 3 + 0] = vb0;
        o_b[(base + k) * 3 + 1] = vb1;
        o_b[(base + k) * 3 + 2] = vb2;
        o_d[base + k]   = vd;
    }
}

extern "C" void kernel_launch(void* const* d_in, const int* in_sizes, int n_in,
                              void* d_out, int out_size, void* d_ws, size_t ws_size,
                              hipStream_t stream) {
    const float* verts = (const float*)d_in[0];
    const int* faces = (const int*)d_in[1];
    float* out = (float*)d_out;
    float4* ws4 = (float4*)d_ws;
    int F = in_sizes[1] / 3;   // 1000
    preprocess_kernel<<<dim3((F + 255) / 256), dim3(256), 0, stream>>>(verts, faces, ws4, F);
    raster_kernel<<<dim3(1024), dim3(512), 0, stream>>>(ws4, out, F);
}

// Round 8
// 84.759 us; speedup vs baseline: 4.5435x; 1.0246x over previous
//
#include <hip/hip_runtime.h>

// SimpleRasterizer: B=1, V=600, F=1000, H=W=128, K=8.
// Round 8: SoA workspace + two-stage (bbox -> edge) staged cull.
//  - kernel A: per-face data into 7 SoA float4 arrays in d_ws:
//      bb4[F] | e0a[F] | e1a[F] | e2a[F] | g4a[F] | g5a[F] | g6a[F]
//    -> every kernel-B staging load is lane-coalesced (16 B x consecutive f),
//    fixing the 112-B-stride AoS pattern (56 lines/wave-load -> 8).
//  - kernel B staging: bbox test from one b128; edge rect-max test only for
//    bbox-passers (exec-masked loads); geometry loads only for keepers.
//  - merge: 5-round __shfl_xor hypercube keep-low-8 (round-7, barrier-free).
// Geometry math identical to validated rounds (fp32, contraction OFF, IEEE div).

#define HW_    128
#define KF     8
#define NPIX   (HW_ * HW_)
#define EPSf   1e-8f
#define BIGf   1e10f
#define SCAP   512     // survivor capacity per tile
#define BBMARG 1e-4f
#define EDGEM  1e-3f

typedef unsigned long long ull;

#define CE(X, Y) { ull _mn = (X) < (Y) ? (X) : (Y); ull _mx = (X) < (Y) ? (Y) : (X); (X) = _mn; (Y) = _mx; }

__device__ __forceinline__ float edge_d2_fn(float px, float py,
                                            float ax, float ay,
                                            float bx, float by) {
#pragma clang fp contract(off)
    float ex = bx - ax;
    float ey = by - ay;
    float l2 = fmaxf(ex * ex + ey * ey, EPSf);
    float t  = ((px - ax) * ex + (py - ay) * ey) / l2;
    t = fminf(fmaxf(t, 0.0f), 1.0f);
    float dx = px - (ax + t * ex);
    float dy = py - (ay + t * ey);
    return dx * dx + dy * dy;
}

// ---------------- kernel A: per-face preprocessing -> SoA ws ----------------
__global__ __launch_bounds__(256) void preprocess_kernel(
    const float* __restrict__ verts,
    const int* __restrict__ faces,
    float4* __restrict__ ws4,
    int F)
{
#pragma clang fp contract(off)
    int f = blockIdx.x * 256 + threadIdx.x;
    if (f >= F) return;
    int i0 = faces[3 * f + 0];
    int i1 = faces[3 * f + 1];
    int i2 = faces[3 * f + 2];
    float x0 = verts[3 * i0 + 0], y0 = verts[3 * i0 + 1], z0 = verts[3 * i0 + 2];
    float x1 = verts[3 * i1 + 0], y1 = verts[3 * i1 + 1], z1 = verts[3 * i1 + 2];
    float x2 = verts[3 * i2 + 0], y2 = verts[3 * i2 + 1], z2 = verts[3 * i2 + 2];
    float area = (x1 - x0) * (y2 - y0) - (y1 - y0) * (x2 - x0);  // exact ref expr
    float s = (area > 0.0f) ? 1.0f : -1.0f;
    // w0 = (x2-x1)(py-y1) - (y2-y1)(px-x1) = A0 + B0*py + C0*px
    float B0 = (x2 - x1), C0 = -(y2 - y1), A0 = (y2 - y1) * x1 - (x2 - x1) * y1;
    float B1 = (x0 - x2), C1 = -(y0 - y2), A1 = (y0 - y2) * x2 - (x0 - x2) * y2;
    float B2 = (x1 - x0), C2 = -(y1 - y0), A2 = (y1 - y0) * x0 - (x1 - x0) * y0;
    ws4[0 * F + f] = make_float4(fminf(x0, fminf(x1, x2)) - BBMARG,
                                 fmaxf(x0, fmaxf(x1, x2)) + BBMARG,
                                 fminf(y0, fminf(y1, y2)) - BBMARG,
                                 fmaxf(y0, fmaxf(y1, y2)) + BBMARG);
    ws4[1 * F + f] = make_float4(s * A0, s * B0, s * C0, 0.0f);
    ws4[2 * F + f] = make_float4(s * A1, s * B1, s * C1, 0.0f);
    ws4[3 * F + f] = make_float4(s * A2, s * B2, s * C2, 0.0f);
    ws4[4 * F + f] = make_float4(x0, y0, x1, y1);
    ws4[5 * F + f] = make_float4(x2, y2, z0, z1);
    ws4[6 * F + f] = make_float4(z2, area, (float)f, 0.0f);
}

// ---------------- kernel B: rasterize ----------------
__global__ __launch_bounds__(512, 8) void raster_kernel(
    const float4* __restrict__ ws4,
    float* __restrict__ out,
    int F)
{
#pragma clang fp contract(off)
    // LDS: compacted geometry only (24 KB) + wave totals
    __shared__ __align__(16) char smem[24608];
    float4*   ga   = (float4*)smem;                    // x0,y0,x1,y1
    float4*   gb   = (float4*)(smem + 8192);           // x2,y2,z0,z1
    float4*   gzf  = (float4*)(smem + 16384);          // z2,area,face_idx,0
    unsigned* wtot = (unsigned*)(smem + 24576);        // per-wave keep counts

    const float4* bb4 = ws4;
    const float4* e0a = ws4 + F;
    const float4* e1a = ws4 + 2 * F;
    const float4* e2a = ws4 + 3 * F;
    const float4* g4a = ws4 + 4 * F;
    const float4* g5a = ws4 + 5 * F;
    const float4* g6a = ws4 + 6 * F;

    int tid  = threadIdx.x;
    int tile = blockIdx.x;                             // 32 x-tiles x 32 y-tiles
    int txi = tile & 31, tyi = tile >> 5;

    // tile NDC rect (pixel-center extremes; px/py decrease with w/h)
    float pxhi = 1.0f - (2.0f * ((float)(txi * 4)     + 0.5f)) / 128.0f;
    float pxlo = 1.0f - (2.0f * ((float)(txi * 4 + 3) + 0.5f)) / 128.0f;
    float pyhi = 1.0f - (2.0f * ((float)(tyi * 4)     + 0.5f)) / 128.0f;
    float pylo = 1.0f - (2.0f * ((float)(tyi * 4 + 3) + 0.5f)) / 128.0f;

    int lane = tid & 63;
    int wv   = tid >> 6;
    int S = 0;                                         // compacted survivor count

    // ---- stage: bbox test -> edge rect-max test -> compaction (all SoA) ----
    for (int fbase = 0; fbase < F; fbase += 512) {
        int f = fbase + tid;
        bool keep = false;
        if (f < F) {
            float4 b4 = bb4[f];                        // coalesced
            bool bo = (b4.x <= pxhi) && (b4.y >= pxlo) && (b4.z <= pyhi) && (b4.w >= pylo);
            if (bo) {                                  // exec-masked loads
                float4 e0 = e0a[f];
                float4 e1 = e1a[f];
                float4 e2 = e2a[f];
                float w0m = e0.x + fmaxf(e0.y * pylo, e0.y * pyhi) + fmaxf(e0.z * pxlo, e0.z * pxhi);
                float w1m = e1.x + fmaxf(e1.y * pylo, e1.y * pyhi) + fmaxf(e1.z * pxlo, e1.z * pxhi);
                float w2m = e2.x + fmaxf(e2.y * pylo, e2.y * pyhi) + fmaxf(e2.z * pxlo, e2.z * pxhi);
                keep = (w0m >= -EDGEM) && (w1m >= -EDGEM) && (w2m >= -EDGEM);
            }
        }
        ull bal = __ballot(keep);
        int below = __popcll(bal & ((1ull << lane) - 1ull));
        if (lane == 0) wtot[wv] = (unsigned)__popcll(bal);
        __syncthreads();
        int pre = 0, tot = 0;
#pragma unroll
        for (int w8 = 0; w8 < 8; ++w8) {
            int t = (int)wtot[w8];
            if (w8 < wv) pre += t;
            tot += t;
        }
        if (keep) {
            int pos = S + pre + below;
            if (pos < SCAP) {
                ga[pos]  = g4a[f];
                gb[pos]  = g5a[f];
                gzf[pos] = g6a[f];
            }
        }
        S += tot;
        if (S > SCAP) S = SCAP;
        __syncthreads();   // wtot reuse next round; final one = geometry visibility
    }

    // ---- main loop: wave = 2 pixels x 32 chunks; lane -> (pixel, chunk) ----
    int p_ = (wv << 1) | (lane >> 5);                  // pixel 0..15 in 4x4 tile
    int c  = lane & 31;                                // chunk 0..31
    int w = txi * 4 + (p_ & 3);
    int h = tyi * 4 + (p_ >> 2);
    float px = 1.0f - (2.0f * ((float)w + 0.5f)) / 128.0f;
    float py = 1.0f - (2.0f * ((float)h + 0.5f)) / 128.0f;

    const ull SENT = ((ull)0x501502F9u << 32) | 0xFFFFFFFFull;  // (bits(1e10), -1)
    ull tk[KF];
#pragma unroll
    for (int k = 0; k < KF; ++k) tk[k] = SENT;

    int j0 = (S * c) >> 5;
    int j1 = (S * (c + 1)) >> 5;
    for (int j = j0; j < j1; ++j) {
        float4 A  = ga[j];
        float4 Bv = gb[j];
        float4 Zf = gzf[j];
        float x0 = A.x,  y0 = A.y,  x1 = A.z,  y1 = A.w;
        float x2 = Bv.x, y2 = Bv.y, z0 = Bv.z, z1 = Bv.w;
        float z2 = Zf.x, area = Zf.y;

        float w0 = (x2 - x1) * (py - y1) - (y2 - y1) * (px - x1);
        float w1 = (x0 - x2) * (py - y2) - (y0 - y2) * (px - x2);
        float w2 = (x1 - x0) * (py - y0) - (y1 - y0) * (px - x0);
        float aabs = fabsf(area);
        // exact sign-equivalent of (w0/area>=0 && w1/area>=0 && w2/area>=0)
        float s = (area > 0.0f) ? 1.0f : -1.0f;
        if (!(w0 * s >= 0.0f && w1 * s >= 0.0f && w2 * s >= 0.0f && aabs > EPSf))
            continue;

        float b0 = w0 / area;
        float b1 = w1 / area;
        float b2 = w2 / area;
        float n0 = b0 * z1 * z2;
        float n1 = z0 * b1 * z2;
        float n2 = z0 * z1 * b2;
        float den = n0 + n1 + n2;
        float dabs = fabsf(den);
        float den_safe = (dabs < EPSf) ? EPSf : den;
        float p0 = n0 / den_safe;
        float p1 = n1 / den_safe;
        float p2 = n2 / den_safe;
        float z = p0 * z0 + p1 * z1 + p2 * z2;

        // u64 (z,idx) key: order-independent stable top-8 insert
        ull key = ((ull)__float_as_uint(z) << 32) | (ull)(unsigned)(int)Zf.z;
        if (key < tk[KF - 1]) {
            tk[KF - 1] = key;
#pragma unroll
            for (int k = KF - 1; k > 0; --k) CE(tk[k - 1], tk[k]);
        }
    }

    // ---- cross-chunk merge: 5-round hypercube shuffle all-reduce, no barriers
#pragma unroll
    for (int d = 1; d < 32; d <<= 1) {
        ull cc[KF];
#pragma unroll
        for (int i = 0; i < KF; ++i) {
            ull bv = (ull)__shfl_xor((long long)tk[KF - 1 - i], d, 64);
            cc[i] = tk[i] < bv ? tk[i] : bv;
        }
        // cc is bitonic; ascending bitonic-merge network (4,2,1)
        CE(cc[0], cc[4]); CE(cc[1], cc[5]); CE(cc[2], cc[6]); CE(cc[3], cc[7]);
        CE(cc[0], cc[2]); CE(cc[1], cc[3]); CE(cc[4], cc[6]); CE(cc[5], cc[7]);
        CE(cc[0], cc[1]); CE(cc[2], cc[3]); CE(cc[4], cc[5]); CE(cc[6], cc[7]);
#pragma unroll
        for (int i = 0; i < KF; ++i) tk[i] = cc[i];
    }
    // all 32 lanes of each pixel-group now hold the identical sorted top-8

    // ---- epilogue: lanes (lane&31)<8 handle slot (lane&7) of their pixel ----
    int sub = lane & 31;
    ull key = tk[0];
#pragma unroll
    for (int k = 1; k < KF; ++k) key = (sub == k) ? tk[k] : key;

    if (sub < KF) {
        int k = sub;
        unsigned idxu = (unsigned)(key & 0xFFFFFFFFULL);
        float zk = __uint_as_float((unsigned)(key >> 32));
        int base = (h * HW_ + w) * KF;

        float vp = -1.0f, vz = -1.0f, vb0 = -1.0f, vb1 = -1.0f, vb2 = -1.0f, vd = -1.0f;
        if (idxu != 0xFFFFFFFFu && zk < 0.5f * BIGf) {
            int f = (int)idxu;
            float4 A4 = g4a[f];
            float4 B4 = g5a[f];
            float4 Z4 = g6a[f];
            float x0 = A4.x, y0 = A4.y, x1 = A4.z, y1 = A4.w;
            float x2 = B4.x, y2 = B4.y, z0 = B4.z, z1 = B4.w;
            float z2 = Z4.x, area = Z4.y;
            float w0 = (x2 - x1) * (py - y1) - (y2 - y1) * (px - x1);
            float w1 = (x0 - x2) * (py - y2) - (y0 - y2) * (px - x2);
            float w2 = (x1 - x0) * (py - y0) - (y1 - y0) * (px - x0);
            float aabs = fabsf(area);
            float area_safe = (aabs < EPSf) ? EPSf : area;
            float b0 = w0 / area_safe;
            float b1 = w1 / area_safe;
            float b2 = w2 / area_safe;
            float n0 = b0 * z1 * z2;
            float n1 = z0 * b1 * z2;
            float n2 = z0 * z1 * b2;
            float den = n0 + n1 + n2;
            float dabs = fabsf(den);
            float den_safe = (dabs < EPSf) ? EPSf : den;
            float p0 = n0 / den_safe;
            float p1 = n1 / den_safe;
            float p2 = n2 / den_safe;
            float e0 = edge_d2_fn(px, py, x0, y0, x1, y1);
            float e1 = edge_d2_fn(px, py, x1, y1, x2, y2);
            float e2 = edge_d2_fn(px, py, x2, y2, x0, y0);
            float d2 = fminf(e0, fminf(e1, e2));
            vp = (float)f;
            vz = zk;
            vb0 = p0; vb1 = p1; vb2 = p2;
            vd = -d2;                       // selected faces are inside
        }

        float* o_pix = out;
        float* o_z   = out + NPIX * KF;
        float* o_b   = out + 2 * NPIX * KF;
        float* o_d   = out + 2 * NPIX * KF + NPIX * KF * 3;
        o_pix[base + k] = vp;
        o_z[base + k]   = vz;
        o_b[(base + k) * 3 + 0] = vb0;
        o_b[(base + k) * 3 + 1] = vb1;
        o_b[(base + k) * 3 + 2] = vb2;
        o_d[base + k]   = vd;
    }
}

extern "C" void kernel_launch(void* const* d_in, const int* in_sizes, int n_in,
                              void* d_out, int out_size, void* d_ws, size_t ws_size,
                              hipStream_t stream) {
    const float* verts = (const float*)d_in[0];
    const int* faces = (const int*)d_in[1];
    float* out = (float*)d_out;
    float4* ws4 = (float4*)d_ws;
    int F = in_sizes[1] / 3;   // 1000
    preprocess_kernel<<<dim3((F + 255) / 256), dim3(256), 0, stream>>>(verts, faces, ws4, F);
    raster_kernel<<<dim3(1024), dim3(512), 0, stream>>>(ws4, out, F);
}

// Round 9
// 81.452 us; speedup vs baseline: 4.7280x; 1.0406x over previous
//
#include <hip/hip_runtime.h>

// SimpleRasterizer: B=1, V=600, F=1000, H=W=128, K=8.
// Round 9: single fused kernel, no workspace.
//  - staging gathers verts/faces directly (19 KB, L1/L2-hot; the harness's
//    268 MB ws poison-fill no longer precedes any load we depend on) and
//    computes bbox + rect-max edge cull inline; both face-slots' loads are
//    hoisted (software-pipelined), 2 barriers total.
//  - top-8 keys = (z_bits, compacted LDS idx): compaction is order-preserving
//    so (z,pos) ordering == (z,face) ordering == stable lax.top_k.
//  - epilogue geometry from LDS (no global re-reads); face id staged as float.
//  - merge: 5-round __shfl_xor hypercube keep-low-8 (round-7, barrier-free).
// Geometry math identical to validated rounds (fp32, contraction OFF, IEEE div).

#define HW_    128
#define KF     8
#define NPIX   (HW_ * HW_)
#define EPSf   1e-8f
#define BIGf   1e10f
#define SCAP   512     // survivor capacity per tile
#define BBMARG 1e-4f
#define EDGEM  1e-3f

typedef unsigned long long ull;

#define CE(X, Y) { ull _mn = (X) < (Y) ? (X) : (Y); ull _mx = (X) < (Y) ? (Y) : (X); (X) = _mn; (Y) = _mx; }

__device__ __forceinline__ float edge_d2_fn(float px, float py,
                                            float ax, float ay,
                                            float bx, float by) {
#pragma clang fp contract(off)
    float ex = bx - ax;
    float ey = by - ay;
    float l2 = fmaxf(ex * ex + ey * ey, EPSf);
    float t  = ((px - ax) * ex + (py - ay) * ey) / l2;
    t = fminf(fmaxf(t, 0.0f), 1.0f);
    float dx = px - (ax + t * ex);
    float dy = py - (ay + t * ey);
    return dx * dx + dy * dy;
}

// conservative tile cull: bbox overlap + rect-max of s*w_e per edge.
// margin EDGEM=1e-3 >> fp eval error -> never culls a reference-inside face.
__device__ __forceinline__ bool tile_keep(
    float x0, float y0, float x1, float y1, float x2, float y2, float area,
    float pxlo, float pxhi, float pylo, float pyhi)
{
#pragma clang fp contract(off)
    float xmn = fminf(x0, fminf(x1, x2)) - BBMARG;
    float xmx = fmaxf(x0, fmaxf(x1, x2)) + BBMARG;
    float ymn = fminf(y0, fminf(y1, y2)) - BBMARG;
    float ymx = fmaxf(y0, fmaxf(y1, y2)) + BBMARG;
    if (!((xmn <= pxhi) && (xmx >= pxlo) && (ymn <= pyhi) && (ymx >= pylo)))
        return false;
    float s = (area > 0.0f) ? 1.0f : -1.0f;
    float B0 = s * (x2 - x1), C0 = -s * (y2 - y1);
    float A0 = s * ((y2 - y1) * x1 - (x2 - x1) * y1);
    float B1 = s * (x0 - x2), C1 = -s * (y0 - y2);
    float A1 = s * ((y0 - y2) * x2 - (x0 - x2) * y2);
    float B2 = s * (x1 - x0), C2 = -s * (y1 - y0);
    float A2 = s * ((y1 - y0) * x0 - (x1 - x0) * y0);
    float w0m = A0 + fmaxf(B0 * pylo, B0 * pyhi) + fmaxf(C0 * pxlo, C0 * pxhi);
    float w1m = A1 + fmaxf(B1 * pylo, B1 * pyhi) + fmaxf(C1 * pxlo, C1 * pxhi);
    float w2m = A2 + fmaxf(B2 * pylo, B2 * pyhi) + fmaxf(C2 * pxlo, C2 * pxhi);
    return (w0m >= -EDGEM) && (w1m >= -EDGEM) && (w2m >= -EDGEM);
}

__global__ __launch_bounds__(512, 8) void raster_kernel(
    const float* __restrict__ verts,
    const int* __restrict__ faces,
    float* __restrict__ out,
    int F)
{
#pragma clang fp contract(off)
    // LDS: compacted geometry (24 KB) + 16 wave totals
    __shared__ __align__(16) char smem[24640];
    float4*   ga   = (float4*)smem;                    // x0,y0,x1,y1
    float4*   gb   = (float4*)(smem + 8192);           // x2,y2,z0,z1
    float4*   gzf  = (float4*)(smem + 16384);          // z2,area,face_idx,0
    unsigned* wtot = (unsigned*)(smem + 24576);        // [0..7]=slotA [8..15]=slotB

    int tid  = threadIdx.x;
    int tile = blockIdx.x;                             // 32 x-tiles x 32 y-tiles
    int txi = tile & 31, tyi = tile >> 5;

    // tile NDC rect (pixel-center extremes; px/py decrease with w/h)
    float pxhi = 1.0f - (2.0f * ((float)(txi * 4)     + 0.5f)) / 128.0f;
    float pxlo = 1.0f - (2.0f * ((float)(txi * 4 + 3) + 0.5f)) / 128.0f;
    float pyhi = 1.0f - (2.0f * ((float)(tyi * 4)     + 0.5f)) / 128.0f;
    float pylo = 1.0f - (2.0f * ((float)(tyi * 4 + 3) + 0.5f)) / 128.0f;

    int lane = tid & 63;
    int wv   = tid >> 6;

    // ---- fused staging: two face-slots, all loads hoisted ----
    int fA = tid;
    int fB = tid + 512;
    bool vA = fA < F;
    bool vB = fB < F;
    int fAc = vA ? fA : 0;
    int fBc = vB ? fB : 0;

    int iA0 = faces[3 * fAc + 0], iA1 = faces[3 * fAc + 1], iA2 = faces[3 * fAc + 2];
    int iB0 = faces[3 * fBc + 0], iB1 = faces[3 * fBc + 1], iB2 = faces[3 * fBc + 2];
    float ax0 = verts[3 * iA0 + 0], ay0 = verts[3 * iA0 + 1], az0 = verts[3 * iA0 + 2];
    float ax1 = verts[3 * iA1 + 0], ay1 = verts[3 * iA1 + 1], az1 = verts[3 * iA1 + 2];
    float ax2 = verts[3 * iA2 + 0], ay2 = verts[3 * iA2 + 1], az2 = verts[3 * iA2 + 2];
    float bx0 = verts[3 * iB0 + 0], by0 = verts[3 * iB0 + 1], bz0 = verts[3 * iB0 + 2];
    float bx1 = verts[3 * iB1 + 0], by1 = verts[3 * iB1 + 1], bz1 = verts[3 * iB1 + 2];
    float bx2 = verts[3 * iB2 + 0], by2 = verts[3 * iB2 + 1], bz2 = verts[3 * iB2 + 2];

    float areaA = (ax1 - ax0) * (ay2 - ay0) - (ay1 - ay0) * (ax2 - ax0);  // exact ref expr
    float areaB = (bx1 - bx0) * (by2 - by0) - (by1 - by0) * (bx2 - bx0);

    bool keepA = vA && tile_keep(ax0, ay0, ax1, ay1, ax2, ay2, areaA,
                                 pxlo, pxhi, pylo, pyhi);
    bool keepB = vB && tile_keep(bx0, by0, bx1, by1, bx2, by2, areaB,
                                 pxlo, pxhi, pylo, pyhi);

    ull balA = __ballot(keepA);
    ull balB = __ballot(keepB);
    ull lmask = (1ull << lane) - 1ull;
    int belowA = __popcll(balA & lmask);
    int belowB = __popcll(balB & lmask);
    if (lane == 0) {
        wtot[wv]     = (unsigned)__popcll(balA);
        wtot[8 + wv] = (unsigned)__popcll(balB);
    }
    __syncthreads();
    int preA = 0, totA = 0, preB = 0, totB = 0;
#pragma unroll
    for (int i = 0; i < 8; ++i) {
        int tA = (int)wtot[i], tB = (int)wtot[8 + i];
        if (i < wv) { preA += tA; preB += tB; }
        totA += tA; totB += tB;
    }
    int S = totA + totB;
    if (S > SCAP) S = SCAP;
    if (keepA) {
        int pos = preA + belowA;
        if (pos < SCAP) {
            ga[pos]  = make_float4(ax0, ay0, ax1, ay1);
            gb[pos]  = make_float4(ax2, ay2, az0, az1);
            gzf[pos] = make_float4(az2, areaA, (float)fA, 0.0f);
        }
    }
    if (keepB) {
        int pos = totA + preB + belowB;
        if (pos < SCAP) {
            ga[pos]  = make_float4(bx0, by0, bx1, by1);
            gb[pos]  = make_float4(bx2, by2, bz0, bz1);
            gzf[pos] = make_float4(bz2, areaB, (float)fB, 0.0f);
        }
    }
    __syncthreads();

    // ---- main loop: wave = 2 pixels x 32 chunks; lane -> (pixel, chunk) ----
    int p_ = (wv << 1) | (lane >> 5);                  // pixel 0..15 in 4x4 tile
    int c  = lane & 31;                                // chunk 0..31
    int w = txi * 4 + (p_ & 3);
    int h = tyi * 4 + (p_ >> 2);
    float px = 1.0f - (2.0f * ((float)w + 0.5f)) / 128.0f;
    float py = 1.0f - (2.0f * ((float)h + 0.5f)) / 128.0f;

    const ull SENT = ((ull)0x501502F9u << 32) | 0xFFFFFFFFull;  // (bits(1e10), -1)
    ull tk[KF];
#pragma unroll
    for (int k = 0; k < KF; ++k) tk[k] = SENT;

    int j0 = (S * c) >> 5;
    int j1 = (S * (c + 1)) >> 5;
    for (int j = j0; j < j1; ++j) {
        float4 A  = ga[j];
        float4 Bv = gb[j];
        float4 Zf = gzf[j];
        float x0 = A.x,  y0 = A.y,  x1 = A.z,  y1 = A.w;
        float x2 = Bv.x, y2 = Bv.y, z0 = Bv.z, z1 = Bv.w;
        float z2 = Zf.x, area = Zf.y;

        float w0 = (x2 - x1) * (py - y1) - (y2 - y1) * (px - x1);
        float w1 = (x0 - x2) * (py - y2) - (y0 - y2) * (px - x2);
        float w2 = (x1 - x0) * (py - y0) - (y1 - y0) * (px - x0);
        float aabs = fabsf(area);
        // exact sign-equivalent of (w0/area>=0 && w1/area>=0 && w2/area>=0)
        float s = (area > 0.0f) ? 1.0f : -1.0f;
        if (!(w0 * s >= 0.0f && w1 * s >= 0.0f && w2 * s >= 0.0f && aabs > EPSf))
            continue;

        float b0 = w0 / area;
        float b1 = w1 / area;
        float b2 = w2 / area;
        float n0 = b0 * z1 * z2;
        float n1 = z0 * b1 * z2;
        float n2 = z0 * z1 * b2;
        float den = n0 + n1 + n2;
        float dabs = fabsf(den);
        float den_safe = (dabs < EPSf) ? EPSf : den;
        float p0 = n0 / den_safe;
        float p1 = n1 / den_safe;
        float p2 = n2 / den_safe;
        float z = p0 * z0 + p1 * z1 + p2 * z2;

        // (z, compacted idx) key: compaction preserves face order -> stable
        ull key = ((ull)__float_as_uint(z) << 32) | (ull)(unsigned)j;
        if (key < tk[KF - 1]) {
            tk[KF - 1] = key;
#pragma unroll
            for (int k = KF - 1; k > 0; --k) CE(tk[k - 1], tk[k]);
        }
    }

    // ---- cross-chunk merge: 5-round hypercube shuffle all-reduce, no barriers
#pragma unroll
    for (int d = 1; d < 32; d <<= 1) {
        ull cc[KF];
#pragma unroll
        for (int i = 0; i < KF; ++i) {
            ull bv = (ull)__shfl_xor((long long)tk[KF - 1 - i], d, 64);
            cc[i] = tk[i] < bv ? tk[i] : bv;
        }
        // cc is bitonic; ascending bitonic-merge network (4,2,1)
        CE(cc[0], cc[4]); CE(cc[1], cc[5]); CE(cc[2], cc[6]); CE(cc[3], cc[7]);
        CE(cc[0], cc[2]); CE(cc[1], cc[3]); CE(cc[4], cc[6]); CE(cc[5], cc[7]);
        CE(cc[0], cc[1]); CE(cc[2], cc[3]); CE(cc[4], cc[5]); CE(cc[6], cc[7]);
#pragma unroll
        for (int i = 0; i < KF; ++i) tk[i] = cc[i];
    }
    // all 32 lanes of each pixel-group now hold the identical sorted top-8

    // ---- epilogue: lanes (lane&31)<8 handle slot (lane&7); geometry from LDS
    int sub = lane & 31;
    ull key = tk[0];
#pragma unroll
    for (int k = 1; k < KF; ++k) key = (sub == k) ? tk[k] : key;

    if (sub < KF) {
        int k = sub;
        unsigned ju = (unsigned)(key & 0xFFFFFFFFULL);
        float zk = __uint_as_float((unsigned)(key >> 32));
        int base = (h * HW_ + w) * KF;

        float vp = -1.0f, vz = -1.0f, vb0 = -1.0f, vb1 = -1.0f, vb2 = -1.0f, vd = -1.0f;
        if (ju != 0xFFFFFFFFu && zk < 0.5f * BIGf) {
            int j = (int)ju;
            float4 A4 = ga[j];
            float4 B4 = gb[j];
            float4 Z4 = gzf[j];
            float x0 = A4.x, y0 = A4.y, x1 = A4.z, y1 = A4.w;
            float x2 = B4.x, y2 = B4.y, z0 = B4.z, z1 = B4.w;
            float z2 = Z4.x, area = Z4.y;
            float w0 = (x2 - x1) * (py - y1) - (y2 - y1) * (px - x1);
            float w1 = (x0 - x2) * (py - y2) - (y0 - y2) * (px - x2);
            float w2 = (x1 - x0) * (py - y0) - (y1 - y0) * (px - x0);
            float aabs = fabsf(area);
            float area_safe = (aabs < EPSf) ? EPSf : area;
            float b0 = w0 / area_safe;
            float b1 = w1 / area_safe;
            float b2 = w2 / area_safe;
            float n0 = b0 * z1 * z2;
            float n1 = z0 * b1 * z2;
            float n2 = z0 * z1 * b2;
            float den = n0 + n1 + n2;
            float dabs = fabsf(den);
            float den_safe = (dabs < EPSf) ? EPSf : den;
            float p0 = n0 / den_safe;
            float p1 = n1 / den_safe;
            float p2 = n2 / den_safe;
            float e0 = edge_d2_fn(px, py, x0, y0, x1, y1);
            float e1 = edge_d2_fn(px, py, x1, y1, x2, y2);
            float e2 = edge_d2_fn(px, py, x2, y2, x0, y0);
            float d2 = fminf(e0, fminf(e1, e2));
            vp = Z4.z;                      // staged (float)face_idx
            vz = zk;
            vb0 = p0; vb1 = p1; vb2 = p2;
            vd = -d2;                       // selected faces are inside
        }

        float* o_pix = out;
        float* o_z   = out + NPIX * KF;
        float* o_b   = out + 2 * NPIX * KF;
        float* o_d   = out + 2 * NPIX * KF + NPIX * KF * 3;
        o_pix[base + k] = vp;
        o_z[base + k]   = vz;
        o_b[(base + k) * 3 + 0] = vb0;
        o_b[(base + k) * 3 + 1] = vb1;
        o_b[(base + k) * 3 + 2] = vb2;
        o_d[base + k]   = vd;
    }
}

extern "C" void kernel_launch(void* const* d_in, const int* in_sizes, int n_in,
                              void* d_out, int out_size, void* d_ws, size_t ws_size,
                              hipStream_t stream) {
    const float* verts = (const float*)d_in[0];
    const int* faces = (const int*)d_in[1];
    float* out = (float*)d_out;
    int F = in_sizes[1] / 3;   // 1000
    raster_kernel<<<dim3(1024), dim3(512), 0, stream>>>(verts, faces, out, F);
}

// Round 10
// 81.349 us; speedup vs baseline: 4.7340x; 1.0013x over previous
//
#include <hip/hip_runtime.h>

// SimpleRasterizer: B=1, V=600, F=1000, H=W=128, K=8.
// Round 10: vertex gather through LDS.
//  - all 1800 vert floats coalesce-loaded into LDS first (4 wave-loads/thread),
//    then the per-face random gather is ds_read (6 cyc, no vmcnt) instead of
//    scattered global_load (~40 lines/wave-load on the L1 path) — kills the
//    staging memory-serialization term introduced by the round-9 fusion.
//  - slots A/B gathered sequentially (lower live-register pressure at wb=8).
//  - everything else = round 9: inline tile cull (bbox + rect-max edges),
//    order-preserving ballot compaction, (z_bits,idx) u64 keys, 5-round
//    __shfl_xor hypercube merge, LDS epilogue. 3 barriers total.
// Geometry math identical to validated rounds (fp32, contraction OFF, IEEE div).

#define HW_    128
#define KF     8
#define NPIX   (HW_ * HW_)
#define EPSf   1e-8f
#define BIGf   1e10f
#define SCAP   512     // survivor capacity per tile
#define BBMARG 1e-4f
#define EDGEM  1e-3f

typedef unsigned long long ull;

#define CE(X, Y) { ull _mn = (X) < (Y) ? (X) : (Y); ull _mx = (X) < (Y) ? (Y) : (X); (X) = _mn; (Y) = _mx; }

__device__ __forceinline__ float edge_d2_fn(float px, float py,
                                            float ax, float ay,
                                            float bx, float by) {
#pragma clang fp contract(off)
    float ex = bx - ax;
    float ey = by - ay;
    float l2 = fmaxf(ex * ex + ey * ey, EPSf);
    float t  = ((px - ax) * ex + (py - ay) * ey) / l2;
    t = fminf(fmaxf(t, 0.0f), 1.0f);
    float dx = px - (ax + t * ex);
    float dy = py - (ay + t * ey);
    return dx * dx + dy * dy;
}

// conservative tile cull: bbox overlap + rect-max of s*w_e per edge.
// margin EDGEM=1e-3 >> fp eval error -> never culls a reference-inside face.
__device__ __forceinline__ bool tile_keep(
    float x0, float y0, float x1, float y1, float x2, float y2, float area,
    float pxlo, float pxhi, float pylo, float pyhi)
{
#pragma clang fp contract(off)
    float xmn = fminf(x0, fminf(x1, x2)) - BBMARG;
    float xmx = fmaxf(x0, fmaxf(x1, x2)) + BBMARG;
    float ymn = fminf(y0, fminf(y1, y2)) - BBMARG;
    float ymx = fmaxf(y0, fmaxf(y1, y2)) + BBMARG;
    if (!((xmn <= pxhi) && (xmx >= pxlo) && (ymn <= pyhi) && (ymx >= pylo)))
        return false;
    float s = (area > 0.0f) ? 1.0f : -1.0f;
    float B0 = s * (x2 - x1), C0 = -s * (y2 - y1);
    float A0 = s * ((y2 - y1) * x1 - (x2 - x1) * y1);
    float B1 = s * (x0 - x2), C1 = -s * (y0 - y2);
    float A1 = s * ((y0 - y2) * x2 - (x0 - x2) * y2);
    float B2 = s * (x1 - x0), C2 = -s * (y1 - y0);
    float A2 = s * ((y1 - y0) * x0 - (x1 - x0) * y0);
    float w0m = A0 + fmaxf(B0 * pylo, B0 * pyhi) + fmaxf(C0 * pxlo, C0 * pxhi);
    float w1m = A1 + fmaxf(B1 * pylo, B1 * pyhi) + fmaxf(C1 * pxlo, C1 * pxhi);
    float w2m = A2 + fmaxf(B2 * pylo, B2 * pyhi) + fmaxf(C2 * pxlo, C2 * pxhi);
    return (w0m >= -EDGEM) && (w1m >= -EDGEM) && (w2m >= -EDGEM);
}

__global__ __launch_bounds__(512, 8) void raster_kernel(
    const float* __restrict__ verts,
    const int* __restrict__ faces,
    float* __restrict__ out,
    int F, int NV3)
{
#pragma clang fp contract(off)
    // LDS: geometry 24 KB | wtot 64 B | staged verts 7.2 KB  -> 31.9 KB
    __shared__ __align__(16) char smem[31872];
    float4*   ga   = (float4*)smem;                    // x0,y0,x1,y1
    float4*   gb   = (float4*)(smem + 8192);           // x2,y2,z0,z1
    float4*   gzf  = (float4*)(smem + 16384);          // z2,area,face_idx,0
    unsigned* wtot = (unsigned*)(smem + 24576);        // [0..7]=slotA [8..15]=slotB
    float*    vlds = (float*)(smem + 24640);           // 1800 floats (verts copy)

    int tid  = threadIdx.x;
    int tile = blockIdx.x;                             // 32 x-tiles x 32 y-tiles
    int txi = tile & 31, tyi = tile >> 5;

    // ---- coalesced verts -> LDS (pure bit-copy) ----
    for (int i = tid; i < NV3; i += 512) vlds[i] = verts[i];

    // tile NDC rect (pixel-center extremes; px/py decrease with w/h)
    float pxhi = 1.0f - (2.0f * ((float)(txi * 4)     + 0.5f)) / 128.0f;
    float pxlo = 1.0f - (2.0f * ((float)(txi * 4 + 3) + 0.5f)) / 128.0f;
    float pyhi = 1.0f - (2.0f * ((float)(tyi * 4)     + 0.5f)) / 128.0f;
    float pylo = 1.0f - (2.0f * ((float)(tyi * 4 + 3) + 0.5f)) / 128.0f;

    int lane = tid & 63;
    int wv   = tid >> 6;
    ull lmask = (1ull << lane) - 1ull;

    // face indices for both slots (coalesced global loads, pre-barrier)
    int fA = tid;
    int fB = tid + 512;
    bool vA = fA < F;
    bool vB = fB < F;
    int fAc = vA ? fA : 0;
    int fBc = vB ? fB : 0;
    int iA0 = faces[3 * fAc + 0], iA1 = faces[3 * fAc + 1], iA2 = faces[3 * fAc + 2];
    int iB0 = faces[3 * fBc + 0], iB1 = faces[3 * fBc + 1], iB2 = faces[3 * fBc + 2];

    __syncthreads();                                   // vlds ready

    // ---- slot A: gather from LDS, cull ----
    float ax0 = vlds[3 * iA0 + 0], ay0 = vlds[3 * iA0 + 1], az0 = vlds[3 * iA0 + 2];
    float ax1 = vlds[3 * iA1 + 0], ay1 = vlds[3 * iA1 + 1], az1 = vlds[3 * iA1 + 2];
    float ax2 = vlds[3 * iA2 + 0], ay2 = vlds[3 * iA2 + 1], az2 = vlds[3 * iA2 + 2];
    float areaA = (ax1 - ax0) * (ay2 - ay0) - (ay1 - ay0) * (ax2 - ax0);  // exact ref expr
    bool keepA = vA && tile_keep(ax0, ay0, ax1, ay1, ax2, ay2, areaA,
                                 pxlo, pxhi, pylo, pyhi);
    ull balA = __ballot(keepA);
    int belowA = __popcll(balA & lmask);

    // ---- slot B: gather from LDS, cull ----
    float bx0 = vlds[3 * iB0 + 0], by0 = vlds[3 * iB0 + 1], bz0 = vlds[3 * iB0 + 2];
    float bx1 = vlds[3 * iB1 + 0], by1 = vlds[3 * iB1 + 1], bz1 = vlds[3 * iB1 + 2];
    float bx2 = vlds[3 * iB2 + 0], by2 = vlds[3 * iB2 + 1], bz2 = vlds[3 * iB2 + 2];
    float areaB = (bx1 - bx0) * (by2 - by0) - (by1 - by0) * (bx2 - bx0);
    bool keepB = vB && tile_keep(bx0, by0, bx1, by1, bx2, by2, areaB,
                                 pxlo, pxhi, pylo, pyhi);
    ull balB = __ballot(keepB);
    int belowB = __popcll(balB & lmask);

    if (lane == 0) {
        wtot[wv]     = (unsigned)__popcll(balA);
        wtot[8 + wv] = (unsigned)__popcll(balB);
    }
    __syncthreads();
    int preA = 0, totA = 0, preB = 0, totB = 0;
#pragma unroll
    for (int i = 0; i < 8; ++i) {
        int tA = (int)wtot[i], tB = (int)wtot[8 + i];
        if (i < wv) { preA += tA; preB += tB; }
        totA += tA; totB += tB;
    }
    int S = totA + totB;
    if (S > SCAP) S = SCAP;
    if (keepA) {
        int pos = preA + belowA;
        if (pos < SCAP) {
            ga[pos]  = make_float4(ax0, ay0, ax1, ay1);
            gb[pos]  = make_float4(ax2, ay2, az0, az1);
            gzf[pos] = make_float4(az2, areaA, (float)fA, 0.0f);
        }
    }
    if (keepB) {
        int pos = totA + preB + belowB;
        if (pos < SCAP) {
            ga[pos]  = make_float4(bx0, by0, bx1, by1);
            gb[pos]  = make_float4(bx2, by2, bz0, bz1);
            gzf[pos] = make_float4(bz2, areaB, (float)fB, 0.0f);
        }
    }
    __syncthreads();

    // ---- main loop: wave = 2 pixels x 32 chunks; lane -> (pixel, chunk) ----
    int p_ = (wv << 1) | (lane >> 5);                  // pixel 0..15 in 4x4 tile
    int c  = lane & 31;                                // chunk 0..31
    int w = txi * 4 + (p_ & 3);
    int h = tyi * 4 + (p_ >> 2);
    float px = 1.0f - (2.0f * ((float)w + 0.5f)) / 128.0f;
    float py = 1.0f - (2.0f * ((float)h + 0.5f)) / 128.0f;

    const ull SENT = ((ull)0x501502F9u << 32) | 0xFFFFFFFFull;  // (bits(1e10), -1)
    ull tk[KF];
#pragma unroll
    for (int k = 0; k < KF; ++k) tk[k] = SENT;

    int j0 = (S * c) >> 5;
    int j1 = (S * (c + 1)) >> 5;
    for (int j = j0; j < j1; ++j) {
        float4 A  = ga[j];
        float4 Bv = gb[j];
        float4 Zf = gzf[j];
        float x0 = A.x,  y0 = A.y,  x1 = A.z,  y1 = A.w;
        float x2 = Bv.x, y2 = Bv.y, z0 = Bv.z, z1 = Bv.w;
        float z2 = Zf.x, area = Zf.y;

        float w0 = (x2 - x1) * (py - y1) - (y2 - y1) * (px - x1);
        float w1 = (x0 - x2) * (py - y2) - (y0 - y2) * (px - x2);
        float w2 = (x1 - x0) * (py - y0) - (y1 - y0) * (px - x0);
        float aabs = fabsf(area);
        // exact sign-equivalent of (w0/area>=0 && w1/area>=0 && w2/area>=0)
        float s = (area > 0.0f) ? 1.0f : -1.0f;
        if (!(w0 * s >= 0.0f && w1 * s >= 0.0f && w2 * s >= 0.0f && aabs > EPSf))
            continue;

        float b0 = w0 / area;
        float b1 = w1 / area;
        float b2 = w2 / area;
        float n0 = b0 * z1 * z2;
        float n1 = z0 * b1 * z2;
        float n2 = z0 * z1 * b2;
        float den = n0 + n1 + n2;
        float dabs = fabsf(den);
        float den_safe = (dabs < EPSf) ? EPSf : den;
        float p0 = n0 / den_safe;
        float p1 = n1 / den_safe;
        float p2 = n2 / den_safe;
        float z = p0 * z0 + p1 * z1 + p2 * z2;

        // (z, compacted idx) key: compaction preserves face order -> stable
        ull key = ((ull)__float_as_uint(z) << 32) | (ull)(unsigned)j;
        if (key < tk[KF - 1]) {
            tk[KF - 1] = key;
#pragma unroll
            for (int k = KF - 1; k > 0; --k) CE(tk[k - 1], tk[k]);
        }
    }

    // ---- cross-chunk merge: 5-round hypercube shuffle all-reduce, no barriers
#pragma unroll
    for (int d = 1; d < 32; d <<= 1) {
        ull cc[KF];
#pragma unroll
        for (int i = 0; i < KF; ++i) {
            ull bv = (ull)__shfl_xor((long long)tk[KF - 1 - i], d, 64);
            cc[i] = tk[i] < bv ? tk[i] : bv;
        }
        // cc is bitonic; ascending bitonic-merge network (4,2,1)
        CE(cc[0], cc[4]); CE(cc[1], cc[5]); CE(cc[2], cc[6]); CE(cc[3], cc[7]);
        CE(cc[0], cc[2]); CE(cc[1], cc[3]); CE(cc[4], cc[6]); CE(cc[5], cc[7]);
        CE(cc[0], cc[1]); CE(cc[2], cc[3]); CE(cc[4], cc[5]); CE(cc[6], cc[7]);
#pragma unroll
        for (int i = 0; i < KF; ++i) tk[i] = cc[i];
    }
    // all 32 lanes of each pixel-group now hold the identical sorted top-8

    // ---- epilogue: lanes (lane&31)<8 handle slot (lane&7); geometry from LDS
    int sub = lane & 31;
    ull key = tk[0];
#pragma unroll
    for (int k = 1; k < KF; ++k) key = (sub == k) ? tk[k] : key;

    if (sub < KF) {
        int k = sub;
        unsigned ju = (unsigned)(key & 0xFFFFFFFFULL);
        float zk = __uint_as_float((unsigned)(key >> 32));
        int base = (h * HW_ + w) * KF;

        float vp = -1.0f, vz = -1.0f, vb0 = -1.0f, vb1 = -1.0f, vb2 = -1.0f, vd = -1.0f;
        if (ju != 0xFFFFFFFFu && zk < 0.5f * BIGf) {
            int j = (int)ju;
            float4 A4 = ga[j];
            float4 B4 = gb[j];
            float4 Z4 = gzf[j];
            float x0 = A4.x, y0 = A4.y, x1 = A4.z, y1 = A4.w;
            float x2 = B4.x, y2 = B4.y, z0 = B4.z, z1 = B4.w;
            float z2 = Z4.x, area = Z4.y;
            float w0 = (x2 - x1) * (py - y1) - (y2 - y1) * (px - x1);
            float w1 = (x0 - x2) * (py - y2) - (y0 - y2) * (px - x2);
            float w2 = (x1 - x0) * (py - y0) - (y1 - y0) * (px - x0);
            float aabs = fabsf(area);
            float area_safe = (aabs < EPSf) ? EPSf : area;
            float b0 = w0 / area_safe;
            float b1 = w1 / area_safe;
            float b2 = w2 / area_safe;
            float n0 = b0 * z1 * z2;
            float n1 = z0 * b1 * z2;
            float n2 = z0 * z1 * b2;
            float den = n0 + n1 + n2;
            float dabs = fabsf(den);
            float den_safe = (dabs < EPSf) ? EPSf : den;
            float p0 = n0 / den_safe;
            float p1 = n1 / den_safe;
            float p2 = n2 / den_safe;
            float e0 = edge_d2_fn(px, py, x0, y0, x1, y1);
            float e1 = edge_d2_fn(px, py, x1, y1, x2, y2);
            float e2 = edge_d2_fn(px, py, x2, y2, x0, y0);
            float d2 = fminf(e0, fminf(e1, e2));
            vp = Z4.z;                      // staged (float)face_idx
            vz = zk;
            vb0 = p0; vb1 = p1; vb2 = p2;
            vd = -d2;                       // selected faces are inside
        }

        float* o_pix = out;
        float* o_z   = out + NPIX * KF;
        float* o_b   = out + 2 * NPIX * KF;
        float* o_d   = out + 2 * NPIX * KF + NPIX * KF * 3;
        o_pix[base + k] = vp;
        o_z[base + k]   = vz;
        o_b[(base + k) * 3 + 0] = vb0;
        o_b[(base + k) * 3 + 1] = vb1;
        o_b[(base + k) * 3 + 2] = vb2;
        o_d[base + k]   = vd;
    }
}

extern "C" void kernel_launch(void* const* d_in, const int* in_sizes, int n_in,
                              void* d_out, int out_size, void* d_ws, size_t ws_size,
                              hipStream_t stream) {
    const float* verts = (const float*)d_in[0];
    const int* faces = (const int*)d_in[1];
    float* out = (float*)d_out;
    int F = in_sizes[1] / 3;     // 1000
    int NV3 = in_sizes[0];       // 1800 floats
    raster_kernel<<<dim3(1024), dim3(512), 0, stream>>>(verts, faces, out, F, NV3);
}